// Round 3
// baseline (12734.582 us; speedup 1.0000x reference)
//
#include <hip/hip_runtime.h>
#include <math.h>

// Problem constants
#define NS 256        // batch N
#define CC 22         // channels c
#define DD 64         // matrix dim d
#define NPOS 4096     // d*d spatial positions
#define NMAT (NS*CC)  // 5632 matrices
#define NSWEEP 10     // one-sided Jacobi sweeps (63 XOR rounds each)

// ---------------------------------------------------------------- embedding MLP (+ constant-channel stats)
__global__ void k_embed(const float* __restrict__ we1, const float* __restrict__ be1,
                        const float* __restrict__ we2, const float* __restrict__ be2,
                        const float* __restrict__ we3, const float* __restrict__ be3,
                        const float* __restrict__ lng, const float* __restrict__ lnb,
                        const int* __restrict__ Mp, float* __restrict__ em3,
                        float* __restrict__ stats1){
  __shared__ float em[10], emln[10], em2[100], e3s[10];
  int tid = threadIdx.x;
  if (tid == 0){
    float md0 = (float)Mp[0] / 500.0f;
    float md1 = 64.0f / 100.0f;
    float mu = 0.f;
    for (int j=0;j<10;++j){ em[j] = md0*we1[j] + md1*we1[10+j] + be1[j]; mu += em[j]; }
    mu *= 0.1f;
    float var = 0.f;
    for (int j=0;j<10;++j){ float d = em[j]-mu; var += d*d; }
    var *= 0.1f;
    float rs = 1.0f/sqrtf(var + 1e-3f);
    for (int j=0;j<10;++j) emln[j] = (em[j]-mu)*rs*lng[j] + lnb[j];
  }
  __syncthreads();
  if (tid < 100){
    float s = be2[tid];
    for (int j=0;j<10;++j) s = fmaf(emln[j], we2[j*100+tid], s);
    em2[tid] = fmaxf(s, 0.f);
  }
  __syncthreads();
  if (tid < 10){
    float s = em[tid] + be3[tid];
    for (int k=0;k<100;++k) s = fmaf(em2[k], we3[k*10+tid], s);
    em3[tid] = s;
    e3s[tid] = s;
  }
  __syncthreads();
  // embedding channels are spatially constant: mean = value, std = 0 -> rstd = 1/1e-3
  for (int idx=tid; idx<NS*10; idx+=256){
    int n = idx/10, j = idx - n*10;
    stats1[(n*32+22+j)*2+0] = e3s[j];
    stats1[(n*32+22+j)*2+1] = 1000.0f;
  }
}

// ---------------------------------------------------------------- one-sided Jacobi on A+sigma*I, 1 wave/matrix
// Lane j owns column j of W. Partner column fetched ONCE per round (t[]),
// reused for dot and rotation: 65 bpermutes/round (was 193). No V carried:
// shift makes the matrix SPD so lambda = ||w|| - sigma, and
// V diag(g) V^T = W diag(g/||w||^2) W^T.
__global__ __launch_bounds__(256) void k_jacobi(const float* __restrict__ x,
                                                float* __restrict__ Wg,
                                                float* __restrict__ nrm2g,
                                                float* __restrict__ sigg){
  const int lane = threadIdx.x & 63;
  const int b = blockIdx.x*4 + (threadIdx.x>>6);
  const float* mat = x + (size_t)b*NPOS;
  float a[64];
  float rsum = 0.f;
  #pragma unroll
  for (int i=0;i<64;++i){
    a[i] = 0.5f*(mat[(i<<6)+lane] + mat[(lane<<6)+i]);
    rsum += fabsf(a[i]);
  }
  // Gershgorin bound: sigma = max_i sum_j |A_ij| + 1  =>  A+sigma*I SPD, lam' >= 1
  #pragma unroll
  for (int off=1; off<64; off<<=1) rsum = fmaxf(rsum, __shfl_xor(rsum, off, 64));
  const float sigma = rsum + 1.0f;
  a[lane] += sigma;

  float own = 0.f;
  #pragma unroll 1
  for (int sw=0; sw<NSWEEP; ++sw){
    own = 0.f;                                  // exact norm refresh per sweep
    #pragma unroll
    for (int i=0;i<64;++i) own = fmaf(a[i], a[i], own);
    #pragma unroll 1
    for (int m=1; m<64; ++m){
      const int pij = ((lane ^ m) << 2);
      float t[64];
      float d = 0.f;
      #pragma unroll
      for (int i=0;i<64;++i){
        t[i] = __int_as_float(__builtin_amdgcn_ds_bpermute(pij, __float_as_int(a[i])));
        d = fmaf(a[i], t[i], d);
      }
      float oth = __int_as_float(__builtin_amdgcn_ds_bpermute(pij, __float_as_int(own)));
      bool rot = (d*d > 1e-14f*own*oth);
      if (__any(rot)){
        float tau = (oth - own)/(2.0f*d);
        float tt  = copysignf(1.0f, tau)/(fabsf(tau) + sqrtf(fmaf(tau,tau,1.0f)));
        float c   = 1.0f/sqrtf(fmaf(tt,tt,1.0f));
        float s   = tt*c;
        if (!rot){ c = 1.0f; s = 0.0f; tt = 0.0f; }   // also kills 0/0 NaN
        own = fmaf(-tt, d, own);
        float ns = -s;
        #pragma unroll
        for (int i=0;i<64;++i) a[i] = fmaf(ns, t[i], c*a[i]);
      }
    }
  }
  float nrm = 0.f;
  #pragma unroll
  for (int i=0;i<64;++i) nrm = fmaf(a[i],a[i],nrm);
  float* wp = Wg + (size_t)b*NPOS;
  #pragma unroll
  for (int i=0;i<64;++i) wp[(i<<6)+lane] = a[i];   // W row-major, coalesced
  nrm2g[(b<<6)+lane] = nrm;
  if (lane == 0) sigg[b] = sigma;
}

// ---------------------------------------------------------------- L = W diag(g/||w||^2) W^T (+ fused channel stats)
#define VP 68   // stride for b128 broadcast rows
#define WP 65   // stride for lane-varying b32 reads (2-way, free)
__global__ __launch_bounds__(256) void k_logm(float* __restrict__ WL,
                                              const float* __restrict__ nrm2g,
                                              const float* __restrict__ sigg,
                                              float* __restrict__ stats1){
  __shared__ float Vr[64*VP];
  __shared__ float Wr[64*WP];
  __shared__ float sc[64];
  __shared__ float red[4][2];
  const int b = blockIdx.x, tid = threadIdx.x;
  float* base = WL + (size_t)b*NPOS;
  if (tid < 64){
    float n2  = nrm2g[(b<<6)+tid];
    float lam = sqrtf(n2) - sigg[b];
    float g   = logf(fmaxf(lam, 1e-4f));
    sc[tid]   = g / n2;
  }
  __syncthreads();
  for (int idx=tid; idx<NPOS; idx+=256){
    int i = idx>>6, j = idx&63;
    float vv = base[idx];
    Vr[i*VP+j] = vv;
    Wr[i*WP+j] = sc[j]*vv;
  }
  __syncthreads();
  float s1 = 0.f, s2 = 0.f;
  for (int idx=tid; idx<NPOS; idx+=256){
    int i = idx>>6, k = idx&63;            // i wave-uniform, k = lane
    const float4* vrow = (const float4*)&Vr[i*VP];
    const float*  wrow = &Wr[k*WP];
    float4 acc = {0.f,0.f,0.f,0.f};
    #pragma unroll
    for (int j=0;j<16;++j){
      float4 a4 = vrow[j];                 // broadcast (same addr all lanes)
      acc.x = fmaf(a4.x, wrow[4*j+0], acc.x);
      acc.y = fmaf(a4.y, wrow[4*j+1], acc.y);
      acc.z = fmaf(a4.z, wrow[4*j+2], acc.z);
      acc.w = fmaf(a4.w, wrow[4*j+3], acc.w);
    }
    float L = (acc.x+acc.y)+(acc.z+acc.w);
    base[idx] = L;                          // overwrite W with L
    s1 += L; s2 = fmaf(L, L, s2);
  }
  // fused per-(n,ch) stats (this block IS one (n,ch) matrix)
  for (int off=32; off; off>>=1){ s1 += __shfl_down(s1,off,64); s2 += __shfl_down(s2,off,64); }
  const int w = tid>>6, lane = tid&63;
  if (lane == 0){ red[w][0] = s1; red[w][1] = s2; }
  __syncthreads();
  if (tid == 0){
    s1 = red[0][0]+red[1][0]+red[2][0]+red[3][0];
    s2 = red[0][1]+red[1][1]+red[2][1]+red[3][1];
    float mean = s1*(1.0f/4096.0f);
    float var  = s2*(1.0f/4096.0f) - mean*mean;
    float sd   = sqrtf(fmaxf(var, 0.f));
    int n = b/CC, ch = b - n*CC;
    stats1[(n*32+ch)*2+0] = mean;
    stats1[(n*32+ch)*2+1] = 1.0f/fmaxf(sd, 1e-3f);
  }
}

// ---------------------------------------------------------------- pass 1: h2 stats (8 positions/thread)
__global__ __launch_bounds__(256,2) void k_pass1(const float* __restrict__ logT,
    const float* __restrict__ em3, const float* __restrict__ stats1,
    const float* __restrict__ w2, const float* __restrict__ b2,
    const float* __restrict__ w3, const float* __restrict__ b3,
    float* __restrict__ s2raw){
  const int n = blockIdx.x;
  const int tid = threadIdx.x;
  const int pp0 = (blockIdx.y<<11) + tid;   // 2 blocks of 2048 positions
  __shared__ float w2s[1024], w3s[1024];
  __shared__ float b2s[32], b3s[32], ms[32], rs[32], e3[10];
  __shared__ float redp[4][64];
  for (int i=tid;i<1024;i+=256){ w2s[i]=w2[i]; w3s[i]=w3[i]; }
  if (tid<32){ b2s[tid]=b2[tid]; b3s[tid]=b3[tid];
    ms[tid]=stats1[(n*32+tid)*2]; rs[tid]=stats1[(n*32+tid)*2+1]; }
  if (tid<10) e3[tid]=em3[tid];
  __syncthreads();
  const float* base = logT + (size_t)n*CC*NPOS;
  float sacc[32], s2acc[32];
  #pragma unroll
  for (int k=0;k<32;++k){ sacc[k]=0.f; s2acc[k]=0.f; }
  #pragma unroll 1
  for (int p=0;p<8;++p){
    const int pos = pp0 + (p<<8);
    float eu[32], t[32];
    #pragma unroll
    for (int c=0;c<22;++c) eu[c] = base[c*NPOS + pos];
    #pragma unroll
    for (int c=0;c<10;++c) eu[22+c] = e3[c];
    #pragma unroll
    for (int k=0;k<32;++k) t[k] = b2s[k];
    #pragma unroll
    for (int j=0;j<32;++j){
      float nj = (eu[j]-ms[j])*rs[j];
      #pragma unroll
      for (int k=0;k<32;++k) t[k] = fmaf(nj, w2s[j*32+k], t[k]);
    }
    #pragma unroll
    for (int k=0;k<32;++k){ t[k] = fmaxf(t[k], 0.f); eu[k] += b3s[k]; }
    #pragma unroll
    for (int j=0;j<32;++j){
      float tj = t[j];
      #pragma unroll
      for (int k=0;k<32;++k) eu[k] = fmaf(tj, w3s[j*32+k], eu[k]);
    }
    #pragma unroll
    for (int k=0;k<32;++k){ sacc[k] += eu[k]; s2acc[k] = fmaf(eu[k],eu[k],s2acc[k]); }
  }
  const int w = tid>>6, lane = tid&63;
  #pragma unroll
  for (int k=0;k<32;++k){
    float v = sacc[k], v2 = s2acc[k];
    for (int off=32; off; off>>=1){ v += __shfl_down(v,off,64); v2 += __shfl_down(v2,off,64); }
    if (lane == 0){ redp[w][2*k] = v; redp[w][2*k+1] = v2; }
  }
  __syncthreads();
  if (tid < 64){
    float v = redp[0][tid]+redp[1][tid]+redp[2][tid]+redp[3][tid];
    atomicAdd(&s2raw[(n<<6)+tid], v);
  }
}

// ---------------------------------------------------------------- finalize h2 stats
__global__ void k_fin2(const float* __restrict__ s2raw, float* __restrict__ stats2){
  int i = blockIdx.x*256 + threadIdx.x;
  if (i < NS*32){
    float s = s2raw[2*i], sq = s2raw[2*i+1];
    float mean = s*(1.0f/4096.0f);
    float var  = sq*(1.0f/4096.0f) - mean*mean;
    float sd   = sqrtf(fmaxf(var, 0.f));
    stats2[2*i]   = mean;
    stats2[2*i+1] = 1.0f/fmaxf(sd, 1e-3f);
  }
}

// ---------------------------------------------------------------- pass 2: h3 accumulation (8 positions/thread)
__global__ __launch_bounds__(256,2) void k_pass2(const float* __restrict__ logT,
    const float* __restrict__ em3, const float* __restrict__ stats1, const float* __restrict__ stats2,
    const float* __restrict__ w2, const float* __restrict__ b2,
    const float* __restrict__ w3, const float* __restrict__ b3,
    const float* __restrict__ w4, const float* __restrict__ b4,
    const float* __restrict__ w5, const float* __restrict__ b5,
    float* __restrict__ cov3){
  const int n = blockIdx.x;
  const int tid = threadIdx.x;
  const int pp0 = (blockIdx.y<<11) + tid;
  __shared__ float w2s[1024], w3s[1024], w4s[1024], w5s[1024];
  __shared__ float b2s[32], b3s[32], b4s[32], b5s[32];
  __shared__ float m1[32], r1[32], m2[32], r2[32], e3[10];
  __shared__ float redp[4][32];
  for (int i=tid;i<1024;i+=256){ w2s[i]=w2[i]; w3s[i]=w3[i]; w4s[i]=w4[i]; w5s[i]=w5[i]; }
  if (tid<32){ b2s[tid]=b2[tid]; b3s[tid]=b3[tid]; b4s[tid]=b4[tid]; b5s[tid]=b5[tid];
    m1[tid]=stats1[(n*32+tid)*2]; r1[tid]=stats1[(n*32+tid)*2+1];
    m2[tid]=stats2[(n*32+tid)*2]; r2[tid]=stats2[(n*32+tid)*2+1]; }
  if (tid<10) e3[tid]=em3[tid];
  __syncthreads();
  const float* base = logT + (size_t)n*CC*NPOS;
  float sacc[32];
  #pragma unroll
  for (int k=0;k<32;++k) sacc[k]=0.f;
  #pragma unroll 1
  for (int p=0;p<8;++p){
    const int pos = pp0 + (p<<8);
    float eu[32], t[32];
    #pragma unroll
    for (int c=0;c<22;++c) eu[c] = base[c*NPOS + pos];
    #pragma unroll
    for (int c=0;c<10;++c) eu[22+c] = e3[c];
    #pragma unroll
    for (int k=0;k<32;++k) t[k] = b2s[k];
    #pragma unroll
    for (int j=0;j<32;++j){
      float nj = (eu[j]-m1[j])*r1[j];
      #pragma unroll
      for (int k=0;k<32;++k) t[k] = fmaf(nj, w2s[j*32+k], t[k]);
    }
    #pragma unroll
    for (int k=0;k<32;++k){ t[k] = fmaxf(t[k], 0.f); eu[k] += b3s[k]; }
    #pragma unroll
    for (int j=0;j<32;++j){
      float tj = t[j];
      #pragma unroll
      for (int k=0;k<32;++k) eu[k] = fmaf(tj, w3s[j*32+k], eu[k]);
    }
    #pragma unroll
    for (int k=0;k<32;++k) t[k] = b4s[k];
    #pragma unroll
    for (int j=0;j<32;++j){
      float nj = (eu[j]-m2[j])*r2[j];
      #pragma unroll
      for (int k=0;k<32;++k) t[k] = fmaf(nj, w4s[j*32+k], t[k]);
    }
    #pragma unroll
    for (int k=0;k<32;++k){ t[k] = fmaxf(t[k], 0.f); eu[k] += b5s[k]; }
    #pragma unroll
    for (int j=0;j<32;++j){
      float tj = t[j];
      #pragma unroll
      for (int k=0;k<32;++k) eu[k] = fmaf(tj, w5s[j*32+k], eu[k]);
    }
    #pragma unroll
    for (int k=0;k<32;++k) sacc[k] += eu[k];
  }
  const int w = tid>>6, lane = tid&63;
  #pragma unroll
  for (int k=0;k<32;++k){
    float v = sacc[k];
    for (int off=32; off; off>>=1) v += __shfl_down(v,off,64);
    if (lane == 0) redp[w][k] = v;
  }
  __syncthreads();
  if (tid < 32){
    float v = redp[0][tid]+redp[1][tid]+redp[2][tid]+redp[3][tid];
    atomicAdd(&cov3[(n<<5)+tid], v);
  }
}

// ---------------------------------------------------------------- head: mean -> matmul -> softmax
__global__ void k_out(const float* __restrict__ cov3, const float* __restrict__ w,
                      float* __restrict__ out){
  __shared__ float wsm[224];
  const int tid = threadIdx.x;
  if (tid < 224) wsm[tid] = w[tid];
  __syncthreads();
  const int n = tid;
  float l[7];
  #pragma unroll
  for (int c=0;c<7;++c) l[c] = 0.f;
  #pragma unroll
  for (int ch=0;ch<32;++ch){
    float v = cov3[(n<<5)+ch]*(1.0f/4096.0f);
    #pragma unroll
    for (int c=0;c<7;++c) l[c] = fmaf(v, wsm[ch*7+c], l[c]);
  }
  float mx = l[0];
  #pragma unroll
  for (int c=1;c<7;++c) mx = fmaxf(mx, l[c]);
  float ssum = 0.f;
  #pragma unroll
  for (int c=0;c<7;++c){ l[c] = expf(l[c]-mx); ssum += l[c]; }
  float inv = 1.0f/ssum;
  #pragma unroll
  for (int c=0;c<7;++c) out[n*7+c] = l[c]*inv;
}

// ----------------------------------------------------------------
extern "C" void kernel_launch(void* const* d_in, const int* in_sizes, int n_in,
                              void* d_out, int out_size, void* d_ws, size_t ws_size,
                              hipStream_t stream){
  const float* x   = (const float*)d_in[0];
  const int*   Mp  = (const int*)  d_in[1];
  const float* w   = (const float*)d_in[2];
  const float* w2  = (const float*)d_in[3];
  const float* b2  = (const float*)d_in[4];
  const float* w3  = (const float*)d_in[5];
  const float* b3  = (const float*)d_in[6];
  const float* w4  = (const float*)d_in[7];
  const float* b4  = (const float*)d_in[8];
  const float* w5  = (const float*)d_in[9];
  const float* b5  = (const float*)d_in[10];
  const float* we1 = (const float*)d_in[11];
  const float* be1 = (const float*)d_in[12];
  const float* we2 = (const float*)d_in[13];
  const float* be2 = (const float*)d_in[14];
  const float* we3 = (const float*)d_in[15];
  const float* be3 = (const float*)d_in[16];
  const float* lng = (const float*)d_in[17];
  const float* lnb = (const float*)d_in[18];

  float* wsf    = (float*)d_ws;
  float* WL     = wsf;                           // [NMAT,4096] W then L in place (92.3 MB)
  float* nrm2g  = WL + (size_t)NMAT*NPOS;        // [NMAT,64]
  float* sigg   = nrm2g + (size_t)NMAT*64;       // [NMAT]
  float* em3    = sigg + NMAT;                   // 16
  float* stats1 = em3 + 16;                      // [N,32,2]
  float* s2raw  = stats1 + NS*64;                // [N,32,2] accum (zeroed)
  float* cov3   = s2raw + NS*64;                 // [N,32]   accum (zeroed)
  float* stats2 = cov3 + NS*32;                  // [N,32,2]

  hipMemsetAsync(s2raw, 0, (size_t)(NS*64 + NS*32)*sizeof(float), stream);

  k_embed <<<1, 256, 0, stream>>>(we1,be1,we2,be2,we3,be3,lng,lnb,Mp,em3,stats1);
  k_jacobi<<<NMAT/4, 256, 0, stream>>>(x, WL, nrm2g, sigg);
  k_logm  <<<NMAT, 256, 0, stream>>>(WL, nrm2g, sigg, stats1);
  k_pass1 <<<dim3(NS,2), 256, 0, stream>>>(WL, em3, stats1, w2,b2,w3,b3, s2raw);
  k_fin2  <<<(NS*32+255)/256, 256, 0, stream>>>(s2raw, stats2);
  k_pass2 <<<dim3(NS,2), 256, 0, stream>>>(WL, em3, stats1, stats2,
                                           w2,b2,w3,b3,w4,b4,w5,b5, cov3);
  k_out   <<<1, 256, 0, stream>>>(cov3, w, (float*)d_out);
}

// Round 4
// 10980.892 us; speedup vs baseline: 1.1597x; 1.1597x over previous
//
#include <hip/hip_runtime.h>
#include <math.h>

// Problem constants
#define NS 256        // batch N
#define CC 22         // channels c
#define DD 64         // matrix dim d
#define NPOS 4096     // d*d spatial positions
#define NMAT (NS*CC)  // 5632 matrices
#define NSWEEP 10     // one-sided Jacobi sweeps (63 XOR rounds each; early-exit on convergence)

// ---------------------------------------------------------------- embedding MLP (+ constant-channel stats)
__global__ void k_embed(const float* __restrict__ we1, const float* __restrict__ be1,
                        const float* __restrict__ we2, const float* __restrict__ be2,
                        const float* __restrict__ we3, const float* __restrict__ be3,
                        const float* __restrict__ lng, const float* __restrict__ lnb,
                        const int* __restrict__ Mp, float* __restrict__ em3,
                        float* __restrict__ stats1){
  __shared__ float em[10], emln[10], em2[100], e3s[10];
  int tid = threadIdx.x;
  if (tid == 0){
    float md0 = (float)Mp[0] / 500.0f;
    float md1 = 64.0f / 100.0f;
    float mu = 0.f;
    for (int j=0;j<10;++j){ em[j] = md0*we1[j] + md1*we1[10+j] + be1[j]; mu += em[j]; }
    mu *= 0.1f;
    float var = 0.f;
    for (int j=0;j<10;++j){ float d = em[j]-mu; var += d*d; }
    var *= 0.1f;
    float rs = 1.0f/sqrtf(var + 1e-3f);
    for (int j=0;j<10;++j) emln[j] = (em[j]-mu)*rs*lng[j] + lnb[j];
  }
  __syncthreads();
  if (tid < 100){
    float s = be2[tid];
    for (int j=0;j<10;++j) s = fmaf(emln[j], we2[j*100+tid], s);
    em2[tid] = fmaxf(s, 0.f);
  }
  __syncthreads();
  if (tid < 10){
    float s = em[tid] + be3[tid];
    for (int k=0;k<100;++k) s = fmaf(em2[k], we3[k*10+tid], s);
    em3[tid] = s;
    e3s[tid] = s;
  }
  __syncthreads();
  // embedding channels are spatially constant: mean = value, std = 0 -> rstd = 1/1e-3
  for (int idx=tid; idx<NS*10; idx+=256){
    int n = idx/10, j = idx - n*10;
    stats1[(n*32+22+j)*2+0] = e3s[j];
    stats1[(n*32+22+j)*2+1] = 1000.0f;
  }
}

// ---------------------------------------------------------------- one-sided Jacobi on A+sigma*I, 1 wave/matrix
// Lane j owns column j of W. Partner column fetched ONCE per round into t[64]
// (registers - launch_bounds(256,1) lifts the VGPR cap that spilled it in r3),
// reused for dot and rotation: 65 bpermutes/round. No V carried: the Gershgorin
// shift makes the matrix SPD so lambda = ||w|| - sigma and
// V diag(g) V^T = W diag(g/||w||^2) W^T.
__global__ __launch_bounds__(256, 1) void k_jacobi(const float* __restrict__ x,
                                                   float* __restrict__ Wg,
                                                   float* __restrict__ nrm2g,
                                                   float* __restrict__ sigg){
  const int lane = threadIdx.x & 63;
  const int b = blockIdx.x*4 + (threadIdx.x>>6);
  const float* mat = x + (size_t)b*NPOS;
  float a[64];
  float rsum = 0.f;
  #pragma unroll
  for (int i=0;i<64;++i){
    a[i] = 0.5f*(mat[(i<<6)+lane] + mat[(lane<<6)+i]);
    rsum += fabsf(a[i]);
  }
  // Gershgorin bound: sigma = max_i sum_j |A_ij| + 1  =>  A+sigma*I SPD, lam' >= 1
  #pragma unroll
  for (int off=1; off<64; off<<=1) rsum = fmaxf(rsum, __shfl_xor(rsum, off, 64));
  const float sigma = rsum + 1.0f;
  a[lane] += sigma;

  float own = 0.f;
  #pragma unroll 1
  for (int sw=0; sw<NSWEEP; ++sw){
    own = 0.f;                                  // exact norm refresh per sweep
    #pragma unroll
    for (int i=0;i<64;++i) own = fmaf(a[i], a[i], own);
    bool sweep_rot = false;
    #pragma unroll 1
    for (int m=1; m<64; ++m){
      const int pij = ((lane ^ m) << 2);
      float t[64];
      float d = 0.f;
      #pragma unroll
      for (int i=0;i<64;++i){
        t[i] = __int_as_float(__builtin_amdgcn_ds_bpermute(pij, __float_as_int(a[i])));
        d = fmaf(a[i], t[i], d);
      }
      float oth = __int_as_float(__builtin_amdgcn_ds_bpermute(pij, __float_as_int(own)));
      bool rot = (d*d > 1e-14f*own*oth);
      if (__any(rot)){
        sweep_rot = true;
        float tau = (oth - own)/(2.0f*d);
        float tt  = copysignf(1.0f, tau)/(fabsf(tau) + sqrtf(fmaf(tau,tau,1.0f)));
        float c   = 1.0f/sqrtf(fmaf(tt,tt,1.0f));
        float s   = tt*c;
        if (!rot){ c = 1.0f; s = 0.0f; tt = 0.0f; }   // also kills 0/0 NaN
        own = fmaf(-tt, d, own);
        float ns = -s;
        #pragma unroll
        for (int i=0;i<64;++i) a[i] = fmaf(ns, t[i], c*a[i]);
      }
    }
    if (!sweep_rot) break;   // converged: no pair rotated this sweep
  }
  float nrm = 0.f;
  #pragma unroll
  for (int i=0;i<64;++i) nrm = fmaf(a[i],a[i],nrm);
  float* wp = Wg + (size_t)b*NPOS;
  #pragma unroll
  for (int i=0;i<64;++i) wp[(i<<6)+lane] = a[i];   // W row-major, coalesced
  nrm2g[(b<<6)+lane] = nrm;
  if (lane == 0) sigg[b] = sigma;
}

// ---------------------------------------------------------------- L = W diag(g/||w||^2) W^T (+ fused channel stats)
#define VP 68   // stride for b128 broadcast rows
#define WP 65   // stride for lane-varying b32 reads (2-way, free)
__global__ __launch_bounds__(256) void k_logm(float* __restrict__ WL,
                                              const float* __restrict__ nrm2g,
                                              const float* __restrict__ sigg,
                                              float* __restrict__ stats1){
  __shared__ float Vr[64*VP];
  __shared__ float Wr[64*WP];
  __shared__ float sc[64];
  __shared__ float red[4][2];
  const int b = blockIdx.x, tid = threadIdx.x;
  float* base = WL + (size_t)b*NPOS;
  if (tid < 64){
    float n2  = nrm2g[(b<<6)+tid];
    float lam = sqrtf(n2) - sigg[b];
    float g   = logf(fmaxf(lam, 1e-4f));
    sc[tid]   = g / n2;
  }
  __syncthreads();
  for (int idx=tid; idx<NPOS; idx+=256){
    int i = idx>>6, j = idx&63;
    float vv = base[idx];
    Vr[i*VP+j] = vv;
    Wr[i*WP+j] = sc[j]*vv;
  }
  __syncthreads();
  float s1 = 0.f, s2 = 0.f;
  for (int idx=tid; idx<NPOS; idx+=256){
    int i = idx>>6, k = idx&63;            // i wave-uniform, k = lane
    const float4* vrow = (const float4*)&Vr[i*VP];
    const float*  wrow = &Wr[k*WP];
    float4 acc = {0.f,0.f,0.f,0.f};
    #pragma unroll
    for (int j=0;j<16;++j){
      float4 a4 = vrow[j];                 // broadcast (same addr all lanes)
      acc.x = fmaf(a4.x, wrow[4*j+0], acc.x);
      acc.y = fmaf(a4.y, wrow[4*j+1], acc.y);
      acc.z = fmaf(a4.z, wrow[4*j+2], acc.z);
      acc.w = fmaf(a4.w, wrow[4*j+3], acc.w);
    }
    float L = (acc.x+acc.y)+(acc.z+acc.w);
    base[idx] = L;                          // overwrite W with L
    s1 += L; s2 = fmaf(L, L, s2);
  }
  // fused per-(n,ch) stats (this block IS one (n,ch) matrix)
  for (int off=32; off; off>>=1){ s1 += __shfl_down(s1,off,64); s2 += __shfl_down(s2,off,64); }
  const int w = tid>>6, lane = tid&63;
  if (lane == 0){ red[w][0] = s1; red[w][1] = s2; }
  __syncthreads();
  if (tid == 0){
    s1 = red[0][0]+red[1][0]+red[2][0]+red[3][0];
    s2 = red[0][1]+red[1][1]+red[2][1]+red[3][1];
    float mean = s1*(1.0f/4096.0f);
    float var  = s2*(1.0f/4096.0f) - mean*mean;
    float sd   = sqrtf(fmaxf(var, 0.f));
    int n = b/CC, ch = b - n*CC;
    stats1[(n*32+ch)*2+0] = mean;
    stats1[(n*32+ch)*2+1] = 1.0f/fmaxf(sd, 1e-3f);
  }
}

// ---------------------------------------------------------------- pass 1: h2 stats (1 position/thread)
__global__ __launch_bounds__(256) void k_pass1(const float* __restrict__ logT,
    const float* __restrict__ em3, const float* __restrict__ stats1,
    const float* __restrict__ w2, const float* __restrict__ b2,
    const float* __restrict__ w3, const float* __restrict__ b3,
    float* __restrict__ s2raw){
  const int n = blockIdx.x;
  const int tid = threadIdx.x;
  const int pp = (blockIdx.y<<8) + tid;
  __shared__ float w2s[1024], w3s[1024];
  __shared__ float b2s[32], b3s[32], ms[32], rs[32], e3[10];
  __shared__ float redp[4][64];
  for (int i=tid;i<1024;i+=256){ w2s[i]=w2[i]; w3s[i]=w3[i]; }
  if (tid<32){ b2s[tid]=b2[tid]; b3s[tid]=b3[tid];
    ms[tid]=stats1[(n*32+tid)*2]; rs[tid]=stats1[(n*32+tid)*2+1]; }
  if (tid<10) e3[tid]=em3[tid];
  __syncthreads();
  float eu[32], t[32];
  const float* base = logT + (size_t)n*CC*NPOS + pp;
  #pragma unroll
  for (int c=0;c<22;++c) eu[c] = base[c*NPOS];
  #pragma unroll
  for (int c=0;c<10;++c) eu[22+c] = e3[c];
  #pragma unroll
  for (int k=0;k<32;++k) t[k] = b2s[k];
  #pragma unroll
  for (int j=0;j<32;++j){
    float nj = (eu[j]-ms[j])*rs[j];
    #pragma unroll
    for (int k=0;k<32;++k) t[k] = fmaf(nj, w2s[j*32+k], t[k]);
  }
  #pragma unroll
  for (int k=0;k<32;++k){ t[k] = fmaxf(t[k], 0.f); eu[k] += b3s[k]; }
  #pragma unroll
  for (int j=0;j<32;++j){
    float tj = t[j];
    #pragma unroll
    for (int k=0;k<32;++k) eu[k] = fmaf(tj, w3s[j*32+k], eu[k]);
  }
  const int w = tid>>6, lane = tid&63;
  #pragma unroll
  for (int k=0;k<32;++k){
    float v = eu[k], v2 = eu[k]*eu[k];
    for (int off=32; off; off>>=1){ v += __shfl_down(v,off,64); v2 += __shfl_down(v2,off,64); }
    if (lane == 0){ redp[w][2*k] = v; redp[w][2*k+1] = v2; }
  }
  __syncthreads();
  if (tid < 64){
    float v = redp[0][tid]+redp[1][tid]+redp[2][tid]+redp[3][tid];
    atomicAdd(&s2raw[(n<<6)+tid], v);
  }
}

// ---------------------------------------------------------------- finalize h2 stats
__global__ void k_fin2(const float* __restrict__ s2raw, float* __restrict__ stats2){
  int i = blockIdx.x*256 + threadIdx.x;
  if (i < NS*32){
    float s = s2raw[2*i], sq = s2raw[2*i+1];
    float mean = s*(1.0f/4096.0f);
    float var  = sq*(1.0f/4096.0f) - mean*mean;
    float sd   = sqrtf(fmaxf(var, 0.f));
    stats2[2*i]   = mean;
    stats2[2*i+1] = 1.0f/fmaxf(sd, 1e-3f);
  }
}

// ---------------------------------------------------------------- pass 2: h3 accumulation (1 position/thread)
__global__ __launch_bounds__(256) void k_pass2(const float* __restrict__ logT,
    const float* __restrict__ em3, const float* __restrict__ stats1, const float* __restrict__ stats2,
    const float* __restrict__ w2, const float* __restrict__ b2,
    const float* __restrict__ w3, const float* __restrict__ b3,
    const float* __restrict__ w4, const float* __restrict__ b4,
    const float* __restrict__ w5, const float* __restrict__ b5,
    float* __restrict__ cov3){
  const int n = blockIdx.x;
  const int tid = threadIdx.x;
  const int pp = (blockIdx.y<<8) + tid;
  __shared__ float w2s[1024], w3s[1024], w4s[1024], w5s[1024];
  __shared__ float b2s[32], b3s[32], b4s[32], b5s[32];
  __shared__ float m1[32], r1[32], m2[32], r2[32], e3[10];
  __shared__ float redp[4][32];
  for (int i=tid;i<1024;i+=256){ w2s[i]=w2[i]; w3s[i]=w3[i]; w4s[i]=w4[i]; w5s[i]=w5[i]; }
  if (tid<32){ b2s[tid]=b2[tid]; b3s[tid]=b3[tid]; b4s[tid]=b4[tid]; b5s[tid]=b5[tid];
    m1[tid]=stats1[(n*32+tid)*2]; r1[tid]=stats1[(n*32+tid)*2+1];
    m2[tid]=stats2[(n*32+tid)*2]; r2[tid]=stats2[(n*32+tid)*2+1]; }
  if (tid<10) e3[tid]=em3[tid];
  __syncthreads();
  float eu[32], t[32];
  const float* base = logT + (size_t)n*CC*NPOS + pp;
  #pragma unroll
  for (int c=0;c<22;++c) eu[c] = base[c*NPOS];
  #pragma unroll
  for (int c=0;c<10;++c) eu[22+c] = e3[c];
  #pragma unroll
  for (int k=0;k<32;++k) t[k] = b2s[k];
  #pragma unroll
  for (int j=0;j<32;++j){
    float nj = (eu[j]-m1[j])*r1[j];
    #pragma unroll
    for (int k=0;k<32;++k) t[k] = fmaf(nj, w2s[j*32+k], t[k]);
  }
  #pragma unroll
  for (int k=0;k<32;++k){ t[k] = fmaxf(t[k], 0.f); eu[k] += b3s[k]; }
  #pragma unroll
  for (int j=0;j<32;++j){
    float tj = t[j];
    #pragma unroll
    for (int k=0;k<32;++k) eu[k] = fmaf(tj, w3s[j*32+k], eu[k]);
  }
  #pragma unroll
  for (int k=0;k<32;++k) t[k] = b4s[k];
  #pragma unroll
  for (int j=0;j<32;++j){
    float nj = (eu[j]-m2[j])*r2[j];
    #pragma unroll
    for (int k=0;k<32;++k) t[k] = fmaf(nj, w4s[j*32+k], t[k]);
  }
  #pragma unroll
  for (int k=0;k<32;++k){ t[k] = fmaxf(t[k], 0.f); eu[k] += b5s[k]; }
  #pragma unroll
  for (int j=0;j<32;++j){
    float tj = t[j];
    #pragma unroll
    for (int k=0;k<32;++k) eu[k] = fmaf(tj, w5s[j*32+k], eu[k]);
  }
  const int w = tid>>6, lane = tid&63;
  #pragma unroll
  for (int k=0;k<32;++k){
    float v = eu[k];
    for (int off=32; off; off>>=1) v += __shfl_down(v,off,64);
    if (lane == 0) redp[w][k] = v;
  }
  __syncthreads();
  if (tid < 32){
    float v = redp[0][tid]+redp[1][tid]+redp[2][tid]+redp[3][tid];
    atomicAdd(&cov3[(n<<5)+tid], v);
  }
}

// ---------------------------------------------------------------- head: mean -> matmul -> softmax
__global__ void k_out(const float* __restrict__ cov3, const float* __restrict__ w,
                      float* __restrict__ out){
  __shared__ float wsm[224];
  const int tid = threadIdx.x;
  if (tid < 224) wsm[tid] = w[tid];
  __syncthreads();
  const int n = tid;
  float l[7];
  #pragma unroll
  for (int c=0;c<7;++c) l[c] = 0.f;
  #pragma unroll
  for (int ch=0;ch<32;++ch){
    float v = cov3[(n<<5)+ch]*(1.0f/4096.0f);
    #pragma unroll
    for (int c=0;c<7;++c) l[c] = fmaf(v, wsm[ch*7+c], l[c]);
  }
  float mx = l[0];
  #pragma unroll
  for (int c=1;c<7;++c) mx = fmaxf(mx, l[c]);
  float ssum = 0.f;
  #pragma unroll
  for (int c=0;c<7;++c){ l[c] = expf(l[c]-mx); ssum += l[c]; }
  float inv = 1.0f/ssum;
  #pragma unroll
  for (int c=0;c<7;++c) out[n*7+c] = l[c]*inv;
}

// ----------------------------------------------------------------
extern "C" void kernel_launch(void* const* d_in, const int* in_sizes, int n_in,
                              void* d_out, int out_size, void* d_ws, size_t ws_size,
                              hipStream_t stream){
  const float* x   = (const float*)d_in[0];
  const int*   Mp  = (const int*)  d_in[1];
  const float* w   = (const float*)d_in[2];
  const float* w2  = (const float*)d_in[3];
  const float* b2  = (const float*)d_in[4];
  const float* w3  = (const float*)d_in[5];
  const float* b3  = (const float*)d_in[6];
  const float* w4  = (const float*)d_in[7];
  const float* b4  = (const float*)d_in[8];
  const float* w5  = (const float*)d_in[9];
  const float* b5  = (const float*)d_in[10];
  const float* we1 = (const float*)d_in[11];
  const float* be1 = (const float*)d_in[12];
  const float* we2 = (const float*)d_in[13];
  const float* be2 = (const float*)d_in[14];
  const float* we3 = (const float*)d_in[15];
  const float* be3 = (const float*)d_in[16];
  const float* lng = (const float*)d_in[17];
  const float* lnb = (const float*)d_in[18];

  float* wsf    = (float*)d_ws;
  float* WL     = wsf;                           // [NMAT,4096] W then L in place (92.3 MB)
  float* nrm2g  = WL + (size_t)NMAT*NPOS;        // [NMAT,64]
  float* sigg   = nrm2g + (size_t)NMAT*64;       // [NMAT]
  float* em3    = sigg + NMAT;                   // 16
  float* stats1 = em3 + 16;                      // [N,32,2]
  float* s2raw  = stats1 + NS*64;                // [N,32,2] accum (zeroed)
  float* cov3   = s2raw + NS*64;                 // [N,32]   accum (zeroed)
  float* stats2 = cov3 + NS*32;                  // [N,32,2]

  hipMemsetAsync(s2raw, 0, (size_t)(NS*64 + NS*32)*sizeof(float), stream);

  k_embed <<<1, 256, 0, stream>>>(we1,be1,we2,be2,we3,be3,lng,lnb,Mp,em3,stats1);
  k_jacobi<<<NMAT/4, 256, 0, stream>>>(x, WL, nrm2g, sigg);
  k_logm  <<<NMAT, 256, 0, stream>>>(WL, nrm2g, sigg, stats1);
  k_pass1 <<<dim3(NS,16), 256, 0, stream>>>(WL, em3, stats1, w2,b2,w3,b3, s2raw);
  k_fin2  <<<(NS*32+255)/256, 256, 0, stream>>>(s2raw, stats2);
  k_pass2 <<<dim3(NS,16), 256, 0, stream>>>(WL, em3, stats1, stats2,
                                            w2,b2,w3,b3,w4,b4,w5,b5, cov3);
  k_out   <<<1, 256, 0, stream>>>(cov3, w, (float*)d_out);
}

// Round 5
// 7774.361 us; speedup vs baseline: 1.6380x; 1.4124x over previous
//
#include <hip/hip_runtime.h>
#include <math.h>

// Problem constants
#define NS 256        // batch N
#define CC 22         // channels c
#define DD 64         // matrix dim d
#define NPOS 4096     // d*d spatial positions
#define NMAT (NS*CC)  // 5632 matrices
#define NSWEEP 10     // one-sided Jacobi sweeps (63 XOR rounds each; early-exit on convergence)

// ---------------------------------------------------------------- embedding MLP (+ constant-channel stats)
__global__ void k_embed(const float* __restrict__ we1, const float* __restrict__ be1,
                        const float* __restrict__ we2, const float* __restrict__ be2,
                        const float* __restrict__ we3, const float* __restrict__ be3,
                        const float* __restrict__ lng, const float* __restrict__ lnb,
                        const int* __restrict__ Mp, float* __restrict__ em3,
                        float* __restrict__ stats1){
  __shared__ float em[10], emln[10], em2[100], e3s[10];
  int tid = threadIdx.x;
  if (tid == 0){
    float md0 = (float)Mp[0] / 500.0f;
    float md1 = 64.0f / 100.0f;
    float mu = 0.f;
    for (int j=0;j<10;++j){ em[j] = md0*we1[j] + md1*we1[10+j] + be1[j]; mu += em[j]; }
    mu *= 0.1f;
    float var = 0.f;
    for (int j=0;j<10;++j){ float d = em[j]-mu; var += d*d; }
    var *= 0.1f;
    float rs = 1.0f/sqrtf(var + 1e-3f);
    for (int j=0;j<10;++j) emln[j] = (em[j]-mu)*rs*lng[j] + lnb[j];
  }
  __syncthreads();
  if (tid < 100){
    float s = be2[tid];
    for (int j=0;j<10;++j) s = fmaf(emln[j], we2[j*100+tid], s);
    em2[tid] = fmaxf(s, 0.f);
  }
  __syncthreads();
  if (tid < 10){
    float s = em[tid] + be3[tid];
    for (int k=0;k<100;++k) s = fmaf(em2[k], we3[k*10+tid], s);
    em3[tid] = s;
    e3s[tid] = s;
  }
  __syncthreads();
  // embedding channels are spatially constant: mean = value, std = 0 -> rstd = 1/1e-3
  for (int idx=tid; idx<NS*10; idx+=256){
    int n = idx/10, j = idx - n*10;
    stats1[(n*32+22+j)*2+0] = e3s[j];
    stats1[(n*32+22+j)*2+1] = 1000.0f;
  }
}

// ---------------------------------------------------------------- one-sided Jacobi on A+sigma*I, 1 wave/matrix
// Lane j owns column j of W in a STATICALLY-indexed register array (any dynamic
// index demotes the whole array to scratch -- r3/r4's 28 GB WRITE_SIZE bug).
// Partner column fetched once per round into t[64], reused for dot + rotation:
// 65 bpermutes/round. No V carried: the Gershgorin shift makes the matrix SPD
// so lambda = ||w|| - sigma and V diag(g) V^T = W diag(g/||w||^2) W^T.
__global__ __launch_bounds__(256, 1) void k_jacobi(const float* __restrict__ x,
                                                   float* __restrict__ Wg,
                                                   float* __restrict__ nrm2g,
                                                   float* __restrict__ sigg){
  const int lane = threadIdx.x & 63;
  const int b = blockIdx.x*4 + (threadIdx.x>>6);
  const float* mat = x + (size_t)b*NPOS;
  float a[64];
  float rsum = 0.f;
  #pragma unroll
  for (int i=0;i<64;++i){
    a[i] = 0.5f*(mat[(i<<6)+lane] + mat[(lane<<6)+i]);
    rsum += fabsf(a[i]);
  }
  // Gershgorin bound: sigma = max_i sum_j |A_ij| + 1  =>  A+sigma*I SPD, lam' >= 1
  #pragma unroll
  for (int off=1; off<64; off<<=1) rsum = fmaxf(rsum, __shfl_xor(rsum, off, 64));
  const float sigma = rsum + 1.0f;
  #pragma unroll
  for (int i=0;i<64;++i) a[i] += (i==lane) ? sigma : 0.0f;   // STATIC index

  float own = 0.f;
  #pragma unroll 1
  for (int sw=0; sw<NSWEEP; ++sw){
    own = 0.f;                                  // exact norm refresh per sweep
    #pragma unroll
    for (int i=0;i<64;++i) own = fmaf(a[i], a[i], own);
    bool sweep_rot = false;
    #pragma unroll 1
    for (int m=1; m<64; ++m){
      const int pij = ((lane ^ m) << 2);
      float t[64];
      float d = 0.f;
      #pragma unroll
      for (int i=0;i<64;++i){
        t[i] = __int_as_float(__builtin_amdgcn_ds_bpermute(pij, __float_as_int(a[i])));
        d = fmaf(a[i], t[i], d);
      }
      float oth = __int_as_float(__builtin_amdgcn_ds_bpermute(pij, __float_as_int(own)));
      bool rot = (d*d > 1e-14f*own*oth);
      if (__any(rot)){
        sweep_rot = true;
        float tau = (oth - own)/(2.0f*d);
        float tt  = copysignf(1.0f, tau)/(fabsf(tau) + sqrtf(fmaf(tau,tau,1.0f)));
        float c   = 1.0f/sqrtf(fmaf(tt,tt,1.0f));
        float s   = tt*c;
        if (!rot){ c = 1.0f; s = 0.0f; tt = 0.0f; }   // also kills 0/0 NaN
        own = fmaf(-tt, d, own);
        float ns = -s;
        #pragma unroll
        for (int i=0;i<64;++i) a[i] = fmaf(ns, t[i], c*a[i]);
      }
    }
    if (!sweep_rot) break;   // converged: no pair rotated this sweep
  }
  float nrm = 0.f;
  #pragma unroll
  for (int i=0;i<64;++i) nrm = fmaf(a[i],a[i],nrm);
  float* wp = Wg + (size_t)b*NPOS;
  #pragma unroll
  for (int i=0;i<64;++i) wp[(i<<6)+lane] = a[i];   // W row-major, coalesced
  nrm2g[(b<<6)+lane] = nrm;
  if (lane == 0) sigg[b] = sigma;
}

// ---------------------------------------------------------------- L = W diag(g/||w||^2) W^T (+ fused channel stats)
#define VP 68   // stride for b128 broadcast rows
#define WP 65   // stride for lane-varying b32 reads (2-way, free)
__global__ __launch_bounds__(256) void k_logm(float* __restrict__ WL,
                                              const float* __restrict__ nrm2g,
                                              const float* __restrict__ sigg,
                                              float* __restrict__ stats1){
  __shared__ float Vr[64*VP];
  __shared__ float Wr[64*WP];
  __shared__ float sc[64];
  __shared__ float red[4][2];
  const int b = blockIdx.x, tid = threadIdx.x;
  float* base = WL + (size_t)b*NPOS;
  if (tid < 64){
    float n2  = nrm2g[(b<<6)+tid];
    float lam = sqrtf(n2) - sigg[b];
    float g   = logf(fmaxf(lam, 1e-4f));
    sc[tid]   = g / n2;
  }
  __syncthreads();
  for (int idx=tid; idx<NPOS; idx+=256){
    int i = idx>>6, j = idx&63;
    float vv = base[idx];
    Vr[i*VP+j] = vv;
    Wr[i*WP+j] = sc[j]*vv;
  }
  __syncthreads();
  float s1 = 0.f, s2 = 0.f;
  for (int idx=tid; idx<NPOS; idx+=256){
    int i = idx>>6, k = idx&63;            // i wave-uniform, k = lane
    const float4* vrow = (const float4*)&Vr[i*VP];
    const float*  wrow = &Wr[k*WP];
    float4 acc = {0.f,0.f,0.f,0.f};
    #pragma unroll
    for (int j=0;j<16;++j){
      float4 a4 = vrow[j];                 // broadcast (same addr all lanes)
      acc.x = fmaf(a4.x, wrow[4*j+0], acc.x);
      acc.y = fmaf(a4.y, wrow[4*j+1], acc.y);
      acc.z = fmaf(a4.z, wrow[4*j+2], acc.z);
      acc.w = fmaf(a4.w, wrow[4*j+3], acc.w);
    }
    float L = (acc.x+acc.y)+(acc.z+acc.w);
    base[idx] = L;                          // overwrite W with L
    s1 += L; s2 = fmaf(L, L, s2);
  }
  // fused per-(n,ch) stats (this block IS one (n,ch) matrix)
  for (int off=32; off; off>>=1){ s1 += __shfl_down(s1,off,64); s2 += __shfl_down(s2,off,64); }
  const int w = tid>>6, lane = tid&63;
  if (lane == 0){ red[w][0] = s1; red[w][1] = s2; }
  __syncthreads();
  if (tid == 0){
    s1 = red[0][0]+red[1][0]+red[2][0]+red[3][0];
    s2 = red[0][1]+red[1][1]+red[2][1]+red[3][1];
    float mean = s1*(1.0f/4096.0f);
    float var  = s2*(1.0f/4096.0f) - mean*mean;
    float sd   = sqrtf(fmaxf(var, 0.f));
    int n = b/CC, ch = b - n*CC;
    stats1[(n*32+ch)*2+0] = mean;
    stats1[(n*32+ch)*2+1] = 1.0f/fmaxf(sd, 1e-3f);
  }
}

// ---------------------------------------------------------------- pass 1: h2 stats (1 position/thread)
__global__ __launch_bounds__(256) void k_pass1(const float* __restrict__ logT,
    const float* __restrict__ em3, const float* __restrict__ stats1,
    const float* __restrict__ w2, const float* __restrict__ b2,
    const float* __restrict__ w3, const float* __restrict__ b3,
    float* __restrict__ s2raw){
  const int n = blockIdx.x;
  const int tid = threadIdx.x;
  const int pp = (blockIdx.y<<8) + tid;
  __shared__ float w2s[1024], w3s[1024];
  __shared__ float b2s[32], b3s[32], ms[32], rs[32], e3[10];
  __shared__ float redp[4][64];
  for (int i=tid;i<1024;i+=256){ w2s[i]=w2[i]; w3s[i]=w3[i]; }
  if (tid<32){ b2s[tid]=b2[tid]; b3s[tid]=b3[tid];
    ms[tid]=stats1[(n*32+tid)*2]; rs[tid]=stats1[(n*32+tid)*2+1]; }
  if (tid<10) e3[tid]=em3[tid];
  __syncthreads();
  float eu[32], t[32];
  const float* base = logT + (size_t)n*CC*NPOS + pp;
  #pragma unroll
  for (int c=0;c<22;++c) eu[c] = base[c*NPOS];
  #pragma unroll
  for (int c=0;c<10;++c) eu[22+c] = e3[c];
  #pragma unroll
  for (int k=0;k<32;++k) t[k] = b2s[k];
  #pragma unroll
  for (int j=0;j<32;++j){
    float nj = (eu[j]-ms[j])*rs[j];
    #pragma unroll
    for (int k=0;k<32;++k) t[k] = fmaf(nj, w2s[j*32+k], t[k]);
  }
  #pragma unroll
  for (int k=0;k<32;++k){ t[k] = fmaxf(t[k], 0.f); eu[k] += b3s[k]; }
  #pragma unroll
  for (int j=0;j<32;++j){
    float tj = t[j];
    #pragma unroll
    for (int k=0;k<32;++k) eu[k] = fmaf(tj, w3s[j*32+k], eu[k]);
  }
  const int w = tid>>6, lane = tid&63;
  #pragma unroll
  for (int k=0;k<32;++k){
    float v = eu[k], v2 = eu[k]*eu[k];
    for (int off=32; off; off>>=1){ v += __shfl_down(v,off,64); v2 += __shfl_down(v2,off,64); }
    if (lane == 0){ redp[w][2*k] = v; redp[w][2*k+1] = v2; }
  }
  __syncthreads();
  if (tid < 64){
    float v = redp[0][tid]+redp[1][tid]+redp[2][tid]+redp[3][tid];
    atomicAdd(&s2raw[(n<<6)+tid], v);
  }
}

// ---------------------------------------------------------------- finalize h2 stats
__global__ void k_fin2(const float* __restrict__ s2raw, float* __restrict__ stats2){
  int i = blockIdx.x*256 + threadIdx.x;
  if (i < NS*32){
    float s = s2raw[2*i], sq = s2raw[2*i+1];
    float mean = s*(1.0f/4096.0f);
    float var  = sq*(1.0f/4096.0f) - mean*mean;
    float sd   = sqrtf(fmaxf(var, 0.f));
    stats2[2*i]   = mean;
    stats2[2*i+1] = 1.0f/fmaxf(sd, 1e-3f);
  }
}

// ---------------------------------------------------------------- pass 2: h3 accumulation (1 position/thread)
__global__ __launch_bounds__(256) void k_pass2(const float* __restrict__ logT,
    const float* __restrict__ em3, const float* __restrict__ stats1, const float* __restrict__ stats2,
    const float* __restrict__ w2, const float* __restrict__ b2,
    const float* __restrict__ w3, const float* __restrict__ b3,
    const float* __restrict__ w4, const float* __restrict__ b4,
    const float* __restrict__ w5, const float* __restrict__ b5,
    float* __restrict__ cov3){
  const int n = blockIdx.x;
  const int tid = threadIdx.x;
  const int pp = (blockIdx.y<<8) + tid;
  __shared__ float w2s[1024], w3s[1024], w4s[1024], w5s[1024];
  __shared__ float b2s[32], b3s[32], b4s[32], b5s[32];
  __shared__ float m1[32], r1[32], m2[32], r2[32], e3[10];
  __shared__ float redp[4][32];
  for (int i=tid;i<1024;i+=256){ w2s[i]=w2[i]; w3s[i]=w3[i]; w4s[i]=w4[i]; w5s[i]=w5[i]; }
  if (tid<32){ b2s[tid]=b2[tid]; b3s[tid]=b3[tid]; b4s[tid]=b4[tid]; b5s[tid]=b5[tid];
    m1[tid]=stats1[(n*32+tid)*2]; r1[tid]=stats1[(n*32+tid)*2+1];
    m2[tid]=stats2[(n*32+tid)*2]; r2[tid]=stats2[(n*32+tid)*2+1]; }
  if (tid<10) e3[tid]=em3[tid];
  __syncthreads();
  float eu[32], t[32];
  const float* base = logT + (size_t)n*CC*NPOS + pp;
  #pragma unroll
  for (int c=0;c<22;++c) eu[c] = base[c*NPOS];
  #pragma unroll
  for (int c=0;c<10;++c) eu[22+c] = e3[c];
  #pragma unroll
  for (int k=0;k<32;++k) t[k] = b2s[k];
  #pragma unroll
  for (int j=0;j<32;++j){
    float nj = (eu[j]-m1[j])*r1[j];
    #pragma unroll
    for (int k=0;k<32;++k) t[k] = fmaf(nj, w2s[j*32+k], t[k]);
  }
  #pragma unroll
  for (int k=0;k<32;++k){ t[k] = fmaxf(t[k], 0.f); eu[k] += b3s[k]; }
  #pragma unroll
  for (int j=0;j<32;++j){
    float tj = t[j];
    #pragma unroll
    for (int k=0;k<32;++k) eu[k] = fmaf(tj, w3s[j*32+k], eu[k]);
  }
  #pragma unroll
  for (int k=0;k<32;++k) t[k] = b4s[k];
  #pragma unroll
  for (int j=0;j<32;++j){
    float nj = (eu[j]-m2[j])*r2[j];
    #pragma unroll
    for (int k=0;k<32;++k) t[k] = fmaf(nj, w4s[j*32+k], t[k]);
  }
  #pragma unroll
  for (int k=0;k<32;++k){ t[k] = fmaxf(t[k], 0.f); eu[k] += b5s[k]; }
  #pragma unroll
  for (int j=0;j<32;++j){
    float tj = t[j];
    #pragma unroll
    for (int k=0;k<32;++k) eu[k] = fmaf(tj, w5s[j*32+k], eu[k]);
  }
  const int w = tid>>6, lane = tid&63;
  #pragma unroll
  for (int k=0;k<32;++k){
    float v = eu[k];
    for (int off=32; off; off>>=1) v += __shfl_down(v,off,64);
    if (lane == 0) redp[w][k] = v;
  }
  __syncthreads();
  if (tid < 32){
    float v = redp[0][tid]+redp[1][tid]+redp[2][tid]+redp[3][tid];
    atomicAdd(&cov3[(n<<5)+tid], v);
  }
}

// ---------------------------------------------------------------- head: mean -> matmul -> softmax
__global__ void k_out(const float* __restrict__ cov3, const float* __restrict__ w,
                      float* __restrict__ out){
  __shared__ float wsm[224];
  const int tid = threadIdx.x;
  if (tid < 224) wsm[tid] = w[tid];
  __syncthreads();
  const int n = tid;
  float l[7];
  #pragma unroll
  for (int c=0;c<7;++c) l[c] = 0.f;
  #pragma unroll
  for (int ch=0;ch<32;++ch){
    float v = cov3[(n<<5)+ch]*(1.0f/4096.0f);
    #pragma unroll
    for (int c=0;c<7;++c) l[c] = fmaf(v, wsm[ch*7+c], l[c]);
  }
  float mx = l[0];
  #pragma unroll
  for (int c=1;c<7;++c) mx = fmaxf(mx, l[c]);
  float ssum = 0.f;
  #pragma unroll
  for (int c=0;c<7;++c){ l[c] = expf(l[c]-mx); ssum += l[c]; }
  float inv = 1.0f/ssum;
  #pragma unroll
  for (int c=0;c<7;++c) out[n*7+c] = l[c]*inv;
}

// ----------------------------------------------------------------
extern "C" void kernel_launch(void* const* d_in, const int* in_sizes, int n_in,
                              void* d_out, int out_size, void* d_ws, size_t ws_size,
                              hipStream_t stream){
  const float* x   = (const float*)d_in[0];
  const int*   Mp  = (const int*)  d_in[1];
  const float* w   = (const float*)d_in[2];
  const float* w2  = (const float*)d_in[3];
  const float* b2  = (const float*)d_in[4];
  const float* w3  = (const float*)d_in[5];
  const float* b3  = (const float*)d_in[6];
  const float* w4  = (const float*)d_in[7];
  const float* b4  = (const float*)d_in[8];
  const float* w5  = (const float*)d_in[9];
  const float* b5  = (const float*)d_in[10];
  const float* we1 = (const float*)d_in[11];
  const float* be1 = (const float*)d_in[12];
  const float* we2 = (const float*)d_in[13];
  const float* be2 = (const float*)d_in[14];
  const float* we3 = (const float*)d_in[15];
  const float* be3 = (const float*)d_in[16];
  const float* lng = (const float*)d_in[17];
  const float* lnb = (const float*)d_in[18];

  float* wsf    = (float*)d_ws;
  float* WL     = wsf;                           // [NMAT,4096] W then L in place (92.3 MB)
  float* nrm2g  = WL + (size_t)NMAT*NPOS;        // [NMAT,64]
  float* sigg   = nrm2g + (size_t)NMAT*64;       // [NMAT]
  float* em3    = sigg + NMAT;                   // 16
  float* stats1 = em3 + 16;                      // [N,32,2]
  float* s2raw  = stats1 + NS*64;                // [N,32,2] accum (zeroed)
  float* cov3   = s2raw + NS*64;                 // [N,32]   accum (zeroed)
  float* stats2 = cov3 + NS*32;                  // [N,32,2]

  hipMemsetAsync(s2raw, 0, (size_t)(NS*64 + NS*32)*sizeof(float), stream);

  k_embed <<<1, 256, 0, stream>>>(we1,be1,we2,be2,we3,be3,lng,lnb,Mp,em3,stats1);
  k_jacobi<<<NMAT/4, 256, 0, stream>>>(x, WL, nrm2g, sigg);
  k_logm  <<<NMAT, 256, 0, stream>>>(WL, nrm2g, sigg, stats1);
  k_pass1 <<<dim3(NS,16), 256, 0, stream>>>(WL, em3, stats1, w2,b2,w3,b3, s2raw);
  k_fin2  <<<(NS*32+255)/256, 256, 0, stream>>>(s2raw, stats2);
  k_pass2 <<<dim3(NS,16), 256, 0, stream>>>(WL, em3, stats1, stats2,
                                            w2,b2,w3,b3,w4,b4,w5,b5, cov3);
  k_out   <<<1, 256, 0, stream>>>(cov3, w, (float*)d_out);
}

// Round 6
// 3157.559 us; speedup vs baseline: 4.0330x; 2.4621x over previous
//
#include <hip/hip_runtime.h>
#include <math.h>

// Problem constants
#define NS 256        // batch N
#define CC 22         // channels c
#define DD 64         // matrix dim d
#define NPOS 4096     // d*d spatial positions
#define NMAT (NS*CC)  // 5632 matrices
#define NSWEEP 10     // one-sided Jacobi sweeps (63 XOR rounds each; early-exit on convergence)
#define EUP 33        // per-thread LDS slot stride: (tid*33+j)%32 -> 2-way (free)

// ---------------------------------------------------------------- embedding MLP (+ constant-channel stats)
__global__ void k_embed(const float* __restrict__ we1, const float* __restrict__ be1,
                        const float* __restrict__ we2, const float* __restrict__ be2,
                        const float* __restrict__ we3, const float* __restrict__ be3,
                        const float* __restrict__ lng, const float* __restrict__ lnb,
                        const int* __restrict__ Mp, float* __restrict__ em3,
                        float* __restrict__ stats1){
  __shared__ float em[10], emln[10], em2[100], e3s[10];
  int tid = threadIdx.x;
  if (tid == 0){
    float md0 = (float)Mp[0] / 500.0f;
    float md1 = 64.0f / 100.0f;
    float mu = 0.f;
    for (int j=0;j<10;++j){ em[j] = md0*we1[j] + md1*we1[10+j] + be1[j]; mu += em[j]; }
    mu *= 0.1f;
    float var = 0.f;
    for (int j=0;j<10;++j){ float d = em[j]-mu; var += d*d; }
    var *= 0.1f;
    float rs = 1.0f/sqrtf(var + 1e-3f);
    for (int j=0;j<10;++j) emln[j] = (em[j]-mu)*rs*lng[j] + lnb[j];
  }
  __syncthreads();
  if (tid < 100){
    float s = be2[tid];
    for (int j=0;j<10;++j) s = fmaf(emln[j], we2[j*100+tid], s);
    em2[tid] = fmaxf(s, 0.f);
  }
  __syncthreads();
  if (tid < 10){
    float s = em[tid] + be3[tid];
    for (int k=0;k<100;++k) s = fmaf(em2[k], we3[k*10+tid], s);
    em3[tid] = s;
    e3s[tid] = s;
  }
  __syncthreads();
  // embedding channels are spatially constant: mean = value, std = 0 -> rstd = 1/1e-3
  for (int idx=tid; idx<NS*10; idx+=256){
    int n = idx/10, j = idx - n*10;
    stats1[(n*32+22+j)*2+0] = e3s[j];
    stats1[(n*32+22+j)*2+1] = 1000.0f;
  }
}

// ---------------------------------------------------------------- one-sided Jacobi on A+sigma*I, 1 wave/matrix
// Lane j owns column j of W in a STATICALLY-indexed register array (any dynamic
// index demotes the whole array to scratch). Partner column fetched once per
// round into t[64], reused for dot + rotation: 65 bpermutes/round. No V: the
// Gershgorin shift makes the matrix SPD so lambda = ||w|| - sigma and
// V diag(g) V^T = W diag(g/||w||^2) W^T.
__global__ __launch_bounds__(256, 1) void k_jacobi(const float* __restrict__ x,
                                                   float* __restrict__ Wg,
                                                   float* __restrict__ nrm2g,
                                                   float* __restrict__ sigg){
  const int lane = threadIdx.x & 63;
  const int b = blockIdx.x*4 + (threadIdx.x>>6);
  const float* mat = x + (size_t)b*NPOS;
  float a[64];
  float rsum = 0.f;
  #pragma unroll
  for (int i=0;i<64;++i){
    a[i] = 0.5f*(mat[(i<<6)+lane] + mat[(lane<<6)+i]);
    rsum += fabsf(a[i]);
  }
  #pragma unroll
  for (int off=1; off<64; off<<=1) rsum = fmaxf(rsum, __shfl_xor(rsum, off, 64));
  const float sigma = rsum + 1.0f;
  #pragma unroll
  for (int i=0;i<64;++i) a[i] += (i==lane) ? sigma : 0.0f;   // STATIC index

  float own = 0.f;
  #pragma unroll 1
  for (int sw=0; sw<NSWEEP; ++sw){
    own = 0.f;                                  // exact norm refresh per sweep
    #pragma unroll
    for (int i=0;i<64;++i) own = fmaf(a[i], a[i], own);
    bool sweep_rot = false;
    #pragma unroll 1
    for (int m=1; m<64; ++m){
      const int pij = ((lane ^ m) << 2);
      float t[64];
      float d = 0.f;
      #pragma unroll
      for (int i=0;i<64;++i){
        t[i] = __int_as_float(__builtin_amdgcn_ds_bpermute(pij, __float_as_int(a[i])));
        d = fmaf(a[i], t[i], d);
      }
      float oth = __int_as_float(__builtin_amdgcn_ds_bpermute(pij, __float_as_int(own)));
      bool rot = (d*d > 1e-14f*own*oth);
      if (__any(rot)){
        sweep_rot = true;
        float tau = (oth - own)/(2.0f*d);
        float tt  = copysignf(1.0f, tau)/(fabsf(tau) + sqrtf(fmaf(tau,tau,1.0f)));
        float c   = 1.0f/sqrtf(fmaf(tt,tt,1.0f));
        float s   = tt*c;
        if (!rot){ c = 1.0f; s = 0.0f; tt = 0.0f; }   // also kills 0/0 NaN
        own = fmaf(-tt, d, own);
        float ns = -s;
        #pragma unroll
        for (int i=0;i<64;++i) a[i] = fmaf(ns, t[i], c*a[i]);
      }
    }
    if (!sweep_rot) break;   // converged
  }
  float nrm = 0.f;
  #pragma unroll
  for (int i=0;i<64;++i) nrm = fmaf(a[i],a[i],nrm);
  float* wp = Wg + (size_t)b*NPOS;
  #pragma unroll
  for (int i=0;i<64;++i) wp[(i<<6)+lane] = a[i];   // W row-major, coalesced
  nrm2g[(b<<6)+lane] = nrm;
  if (lane == 0) sigg[b] = sigma;
}

// ---------------------------------------------------------------- L = W diag(g/||w||^2) W^T (+ fused channel stats)
#define VP 68   // stride for b128 broadcast rows
#define WP 65   // stride for lane-varying b32 reads (2-way, free)
__global__ __launch_bounds__(256) void k_logm(float* __restrict__ WL,
                                              const float* __restrict__ nrm2g,
                                              const float* __restrict__ sigg,
                                              float* __restrict__ stats1){
  __shared__ alignas(16) float Vr[64*VP];
  __shared__ float Wr[64*WP];
  __shared__ float sc[64];
  __shared__ float red[4][2];
  const int b = blockIdx.x, tid = threadIdx.x;
  float* base = WL + (size_t)b*NPOS;
  if (tid < 64){
    float n2  = nrm2g[(b<<6)+tid];
    float lam = sqrtf(n2) - sigg[b];
    float g   = logf(fmaxf(lam, 1e-4f));
    sc[tid]   = g / n2;
  }
  __syncthreads();
  for (int idx=tid; idx<NPOS; idx+=256){
    int i = idx>>6, j = idx&63;
    float vv = base[idx];
    Vr[i*VP+j] = vv;
    Wr[i*WP+j] = sc[j]*vv;
  }
  __syncthreads();
  float s1 = 0.f, s2 = 0.f;
  for (int idx=tid; idx<NPOS; idx+=256){
    int i = idx>>6, k = idx&63;            // i wave-uniform, k = lane
    const float4* vrow = (const float4*)&Vr[i*VP];
    const float*  wrow = &Wr[k*WP];
    float4 acc = {0.f,0.f,0.f,0.f};
    #pragma unroll
    for (int j=0;j<16;++j){
      float4 a4 = vrow[j];                 // broadcast (same addr all lanes)
      acc.x = fmaf(a4.x, wrow[4*j+0], acc.x);
      acc.y = fmaf(a4.y, wrow[4*j+1], acc.y);
      acc.z = fmaf(a4.z, wrow[4*j+2], acc.z);
      acc.w = fmaf(a4.w, wrow[4*j+3], acc.w);
    }
    float L = (acc.x+acc.y)+(acc.z+acc.w);
    base[idx] = L;                          // overwrite W with L
    s1 += L; s2 = fmaf(L, L, s2);
  }
  for (int off=32; off; off>>=1){ s1 += __shfl_down(s1,off,64); s2 += __shfl_down(s2,off,64); }
  const int w = tid>>6, lane = tid&63;
  if (lane == 0){ red[w][0] = s1; red[w][1] = s2; }
  __syncthreads();
  if (tid == 0){
    s1 = red[0][0]+red[1][0]+red[2][0]+red[3][0];
    s2 = red[0][1]+red[1][1]+red[2][1]+red[3][1];
    float mean = s1*(1.0f/4096.0f);
    float var  = s2*(1.0f/4096.0f) - mean*mean;
    float sd   = sqrtf(fmaxf(var, 0.f));
    int n = b/CC, ch = b - n*CC;
    stats1[(n*32+ch)*2+0] = mean;
    stats1[(n*32+ch)*2+1] = 1.0f/fmaxf(sd, 1e-3f);
  }
}

// ---------------------------------------------------------------- pass 1: h2 stats
// Dynamic-j operands (nj, relu'd t) live in a per-thread LDS slot so the
// j-loops stay ROLLED while register accumulators t[k]/eu[k] stay STATIC —
// this kills the r5 spill (VGPR 256 + 2.5 GB scratch each way).
__global__ __launch_bounds__(256) void k_pass1(const float* __restrict__ logT,
    const float* __restrict__ em3, const float* __restrict__ stats1,
    const float* __restrict__ w2, const float* __restrict__ b2,
    const float* __restrict__ w3, const float* __restrict__ b3,
    float* __restrict__ s2raw){
  const int n = blockIdx.x;
  const int tid = threadIdx.x;
  const int pp = (blockIdx.y<<8) + tid;
  __shared__ alignas(16) float w2s[1024];
  __shared__ alignas(16) float w3s[1024];
  __shared__ float b2s[32], b3s[32], ms[32], rs[32], e3[10];
  __shared__ float eus[256*EUP];
  __shared__ float redp[4][64];
  for (int i=tid;i<1024;i+=256){ w2s[i]=w2[i]; w3s[i]=w3[i]; }
  if (tid<32){ b2s[tid]=b2[tid]; b3s[tid]=b3[tid];
    ms[tid]=stats1[(n*32+tid)*2]; rs[tid]=stats1[(n*32+tid)*2+1]; }
  if (tid<10) e3[tid]=em3[tid];
  __syncthreads();
  float eu[32], t[32];
  float* myeu = eus + tid*EUP;
  const float* base = logT + (size_t)n*CC*NPOS + pp;
  #pragma unroll
  for (int c=0;c<22;++c) eu[c] = base[c*NPOS];
  #pragma unroll
  for (int c=0;c<10;++c) eu[22+c] = e3[c];
  // stage normalized inputs to LDS (static indices on eu)
  #pragma unroll
  for (int j=0;j<32;++j) myeu[j] = (eu[j]-ms[j])*rs[j];
  #pragma unroll
  for (int k=0;k<32;++k) t[k] = b2s[k];
  #pragma unroll 1
  for (int j=0;j<32;++j){
    float nj = myeu[j];
    const float4* wr = (const float4*)(w2s + (j<<5));
    #pragma unroll
    for (int q=0;q<8;++q){
      float4 w4 = wr[q];
      t[4*q+0] = fmaf(nj, w4.x, t[4*q+0]);
      t[4*q+1] = fmaf(nj, w4.y, t[4*q+1]);
      t[4*q+2] = fmaf(nj, w4.z, t[4*q+2]);
      t[4*q+3] = fmaf(nj, w4.w, t[4*q+3]);
    }
  }
  // stage relu(t) to LDS, then residual matmul with rolled j
  #pragma unroll
  for (int k=0;k<32;++k) myeu[k] = fmaxf(t[k], 0.f);
  #pragma unroll
  for (int k=0;k<32;++k) eu[k] += b3s[k];
  #pragma unroll 1
  for (int j=0;j<32;++j){
    float tj = myeu[j];
    const float4* wr = (const float4*)(w3s + (j<<5));
    #pragma unroll
    for (int q=0;q<8;++q){
      float4 w4 = wr[q];
      eu[4*q+0] = fmaf(tj, w4.x, eu[4*q+0]);
      eu[4*q+1] = fmaf(tj, w4.y, eu[4*q+1]);
      eu[4*q+2] = fmaf(tj, w4.z, eu[4*q+2]);
      eu[4*q+3] = fmaf(tj, w4.w, eu[4*q+3]);
    }
  }
  // eu is h2; per-channel sum/sumsq reduce
  const int w = tid>>6, lane = tid&63;
  #pragma unroll
  for (int k=0;k<32;++k){
    float v = eu[k], v2 = eu[k]*eu[k];
    for (int off=32; off; off>>=1){ v += __shfl_down(v,off,64); v2 += __shfl_down(v2,off,64); }
    if (lane == 0){ redp[w][2*k] = v; redp[w][2*k+1] = v2; }
  }
  __syncthreads();
  if (tid < 64){
    float v = redp[0][tid]+redp[1][tid]+redp[2][tid]+redp[3][tid];
    atomicAdd(&s2raw[(n<<6)+tid], v);
  }
}

// ---------------------------------------------------------------- finalize h2 stats
__global__ void k_fin2(const float* __restrict__ s2raw, float* __restrict__ stats2){
  int i = blockIdx.x*256 + threadIdx.x;
  if (i < NS*32){
    float s = s2raw[2*i], sq = s2raw[2*i+1];
    float mean = s*(1.0f/4096.0f);
    float var  = sq*(1.0f/4096.0f) - mean*mean;
    float sd   = sqrtf(fmaxf(var, 0.f));
    stats2[2*i]   = mean;
    stats2[2*i+1] = 1.0f/fmaxf(sd, 1e-3f);
  }
}

// ---------------------------------------------------------------- pass 2: h3 accumulation (same rolled-j structure)
__global__ __launch_bounds__(256) void k_pass2(const float* __restrict__ logT,
    const float* __restrict__ em3, const float* __restrict__ stats1, const float* __restrict__ stats2,
    const float* __restrict__ w2, const float* __restrict__ b2,
    const float* __restrict__ w3, const float* __restrict__ b3,
    const float* __restrict__ w4, const float* __restrict__ b4,
    const float* __restrict__ w5, const float* __restrict__ b5,
    float* __restrict__ cov3){
  const int n = blockIdx.x;
  const int tid = threadIdx.x;
  const int pp = (blockIdx.y<<8) + tid;
  __shared__ alignas(16) float w2s[1024];
  __shared__ alignas(16) float w3s[1024];
  __shared__ alignas(16) float w4s[1024];
  __shared__ alignas(16) float w5s[1024];
  __shared__ float b2s[32], b3s[32], b4s[32], b5s[32];
  __shared__ float m1[32], r1[32], m2[32], r2[32], e3[10];
  __shared__ float eus[256*EUP];
  __shared__ float redp[4][32];
  for (int i=tid;i<1024;i+=256){ w2s[i]=w2[i]; w3s[i]=w3[i]; w4s[i]=w4[i]; w5s[i]=w5[i]; }
  if (tid<32){ b2s[tid]=b2[tid]; b3s[tid]=b3[tid]; b4s[tid]=b4[tid]; b5s[tid]=b5[tid];
    m1[tid]=stats1[(n*32+tid)*2]; r1[tid]=stats1[(n*32+tid)*2+1];
    m2[tid]=stats2[(n*32+tid)*2]; r2[tid]=stats2[(n*32+tid)*2+1]; }
  if (tid<10) e3[tid]=em3[tid];
  __syncthreads();
  float eu[32], t[32];
  float* myeu = eus + tid*EUP;
  const float* base = logT + (size_t)n*CC*NPOS + pp;
  #pragma unroll
  for (int c=0;c<22;++c) eu[c] = base[c*NPOS];
  #pragma unroll
  for (int c=0;c<10;++c) eu[22+c] = e3[c];
  // --- block 1: h2 = eu + relu(matnorm(eu)@w2+b2)@w3 + b3 ---
  #pragma unroll
  for (int j=0;j<32;++j) myeu[j] = (eu[j]-m1[j])*r1[j];
  #pragma unroll
  for (int k=0;k<32;++k) t[k] = b2s[k];
  #pragma unroll 1
  for (int j=0;j<32;++j){
    float nj = myeu[j];
    const float4* wr = (const float4*)(w2s + (j<<5));
    #pragma unroll
    for (int q=0;q<8;++q){
      float4 w4v = wr[q];
      t[4*q+0] = fmaf(nj, w4v.x, t[4*q+0]);
      t[4*q+1] = fmaf(nj, w4v.y, t[4*q+1]);
      t[4*q+2] = fmaf(nj, w4v.z, t[4*q+2]);
      t[4*q+3] = fmaf(nj, w4v.w, t[4*q+3]);
    }
  }
  #pragma unroll
  for (int k=0;k<32;++k) myeu[k] = fmaxf(t[k], 0.f);
  #pragma unroll
  for (int k=0;k<32;++k) eu[k] += b3s[k];
  #pragma unroll 1
  for (int j=0;j<32;++j){
    float tj = myeu[j];
    const float4* wr = (const float4*)(w3s + (j<<5));
    #pragma unroll
    for (int q=0;q<8;++q){
      float4 w4v = wr[q];
      eu[4*q+0] = fmaf(tj, w4v.x, eu[4*q+0]);
      eu[4*q+1] = fmaf(tj, w4v.y, eu[4*q+1]);
      eu[4*q+2] = fmaf(tj, w4v.z, eu[4*q+2]);
      eu[4*q+3] = fmaf(tj, w4v.w, eu[4*q+3]);
    }
  }
  // --- block 2: h3 = h2 + relu(matnorm(h2)@w4+b4)@w5 + b5 ---
  #pragma unroll
  for (int j=0;j<32;++j) myeu[j] = (eu[j]-m2[j])*r2[j];
  #pragma unroll
  for (int k=0;k<32;++k) t[k] = b4s[k];
  #pragma unroll 1
  for (int j=0;j<32;++j){
    float nj = myeu[j];
    const float4* wr = (const float4*)(w4s + (j<<5));
    #pragma unroll
    for (int q=0;q<8;++q){
      float4 w4v = wr[q];
      t[4*q+0] = fmaf(nj, w4v.x, t[4*q+0]);
      t[4*q+1] = fmaf(nj, w4v.y, t[4*q+1]);
      t[4*q+2] = fmaf(nj, w4v.z, t[4*q+2]);
      t[4*q+3] = fmaf(nj, w4v.w, t[4*q+3]);
    }
  }
  #pragma unroll
  for (int k=0;k<32;++k) myeu[k] = fmaxf(t[k], 0.f);
  #pragma unroll
  for (int k=0;k<32;++k) eu[k] += b5s[k];
  #pragma unroll 1
  for (int j=0;j<32;++j){
    float tj = myeu[j];
    const float4* wr = (const float4*)(w5s + (j<<5));
    #pragma unroll
    for (int q=0;q<8;++q){
      float4 w4v = wr[q];
      eu[4*q+0] = fmaf(tj, w4v.x, eu[4*q+0]);
      eu[4*q+1] = fmaf(tj, w4v.y, eu[4*q+1]);
      eu[4*q+2] = fmaf(tj, w4v.z, eu[4*q+2]);
      eu[4*q+3] = fmaf(tj, w4v.w, eu[4*q+3]);
    }
  }
  // eu is h3; accumulate per-channel spatial sums
  const int w = tid>>6, lane = tid&63;
  #pragma unroll
  for (int k=0;k<32;++k){
    float v = eu[k];
    for (int off=32; off; off>>=1) v += __shfl_down(v,off,64);
    if (lane == 0) redp[w][k] = v;
  }
  __syncthreads();
  if (tid < 32){
    float v = redp[0][tid]+redp[1][tid]+redp[2][tid]+redp[3][tid];
    atomicAdd(&cov3[(n<<5)+tid], v);
  }
}

// ---------------------------------------------------------------- head: mean -> matmul -> softmax
__global__ void k_out(const float* __restrict__ cov3, const float* __restrict__ w,
                      float* __restrict__ out){
  __shared__ float wsm[224];
  const int tid = threadIdx.x;
  if (tid < 224) wsm[tid] = w[tid];
  __syncthreads();
  const int n = tid;
  float l[7];
  #pragma unroll
  for (int c=0;c<7;++c) l[c] = 0.f;
  #pragma unroll
  for (int ch=0;ch<32;++ch){
    float v = cov3[(n<<5)+ch]*(1.0f/4096.0f);
    #pragma unroll
    for (int c=0;c<7;++c) l[c] = fmaf(v, wsm[ch*7+c], l[c]);
  }
  float mx = l[0];
  #pragma unroll
  for (int c=1;c<7;++c) mx = fmaxf(mx, l[c]);
  float ssum = 0.f;
  #pragma unroll
  for (int c=0;c<7;++c){ l[c] = expf(l[c]-mx); ssum += l[c]; }
  float inv = 1.0f/ssum;
  #pragma unroll
  for (int c=0;c<7;++c) out[n*7+c] = l[c]*inv;
}

// ----------------------------------------------------------------
extern "C" void kernel_launch(void* const* d_in, const int* in_sizes, int n_in,
                              void* d_out, int out_size, void* d_ws, size_t ws_size,
                              hipStream_t stream){
  const float* x   = (const float*)d_in[0];
  const int*   Mp  = (const int*)  d_in[1];
  const float* w   = (const float*)d_in[2];
  const float* w2  = (const float*)d_in[3];
  const float* b2  = (const float*)d_in[4];
  const float* w3  = (const float*)d_in[5];
  const float* b3  = (const float*)d_in[6];
  const float* w4  = (const float*)d_in[7];
  const float* b4  = (const float*)d_in[8];
  const float* w5  = (const float*)d_in[9];
  const float* b5  = (const float*)d_in[10];
  const float* we1 = (const float*)d_in[11];
  const float* be1 = (const float*)d_in[12];
  const float* we2 = (const float*)d_in[13];
  const float* be2 = (const float*)d_in[14];
  const float* we3 = (const float*)d_in[15];
  const float* be3 = (const float*)d_in[16];
  const float* lng = (const float*)d_in[17];
  const float* lnb = (const float*)d_in[18];

  float* wsf    = (float*)d_ws;
  float* WL     = wsf;                           // [NMAT,4096] W then L in place (92.3 MB)
  float* nrm2g  = WL + (size_t)NMAT*NPOS;        // [NMAT,64]
  float* sigg   = nrm2g + (size_t)NMAT*64;       // [NMAT]
  float* em3    = sigg + NMAT;                   // 16
  float* stats1 = em3 + 16;                      // [N,32,2]
  float* s2raw  = stats1 + NS*64;                // [N,32,2] accum (zeroed)
  float* cov3   = s2raw + NS*64;                 // [N,32]   accum (zeroed)
  float* stats2 = cov3 + NS*32;                  // [N,32,2]

  hipMemsetAsync(s2raw, 0, (size_t)(NS*64 + NS*32)*sizeof(float), stream);

  k_embed <<<1, 256, 0, stream>>>(we1,be1,we2,be2,we3,be3,lng,lnb,Mp,em3,stats1);
  k_jacobi<<<NMAT/4, 256, 0, stream>>>(x, WL, nrm2g, sigg);
  k_logm  <<<NMAT, 256, 0, stream>>>(WL, nrm2g, sigg, stats1);
  k_pass1 <<<dim3(NS,16), 256, 0, stream>>>(WL, em3, stats1, w2,b2,w3,b3, s2raw);
  k_fin2  <<<(NS*32+255)/256, 256, 0, stream>>>(s2raw, stats2);
  k_pass2 <<<dim3(NS,16), 256, 0, stream>>>(WL, em3, stats1, stats2,
                                            w2,b2,w3,b3,w4,b4,w5,b5, cov3);
  k_out   <<<1, 256, 0, stream>>>(cov3, w, (float*)d_out);
}

// Round 7
// 2415.443 us; speedup vs baseline: 5.2722x; 1.3072x over previous
//
#include <hip/hip_runtime.h>
#include <math.h>

// Problem constants
#define NS 256        // batch N
#define CC 22         // channels c
#define DD 64         // matrix dim d
#define NPOS 4096     // d*d spatial positions
#define NMAT (NS*CC)  // 5632 matrices
#define NSWEEP 10     // one-sided Jacobi sweeps (63 XOR rounds each; early-exit on convergence)
#define EUP 33        // per-thread LDS slot stride: (tid*33+j)%32 -> 2-way (free)
#define JCOL 68       // jacobi LDS column stride (floats): 16B-aligned, 8 lanes/bank for b128

// ---------------------------------------------------------------- embedding MLP (+ constant-channel stats)
__global__ void k_embed(const float* __restrict__ we1, const float* __restrict__ be1,
                        const float* __restrict__ we2, const float* __restrict__ be2,
                        const float* __restrict__ we3, const float* __restrict__ be3,
                        const float* __restrict__ lng, const float* __restrict__ lnb,
                        const int* __restrict__ Mp, float* __restrict__ em3,
                        float* __restrict__ stats1){
  __shared__ float em[10], emln[10], em2[100], e3s[10];
  int tid = threadIdx.x;
  if (tid == 0){
    float md0 = (float)Mp[0] / 500.0f;
    float md1 = 64.0f / 100.0f;
    float mu = 0.f;
    for (int j=0;j<10;++j){ em[j] = md0*we1[j] + md1*we1[10+j] + be1[j]; mu += em[j]; }
    mu *= 0.1f;
    float var = 0.f;
    for (int j=0;j<10;++j){ float d = em[j]-mu; var += d*d; }
    var *= 0.1f;
    float rs = 1.0f/sqrtf(var + 1e-3f);
    for (int j=0;j<10;++j) emln[j] = (em[j]-mu)*rs*lng[j] + lnb[j];
  }
  __syncthreads();
  if (tid < 100){
    float s = be2[tid];
    for (int j=0;j<10;++j) s = fmaf(emln[j], we2[j*100+tid], s);
    em2[tid] = fmaxf(s, 0.f);
  }
  __syncthreads();
  if (tid < 10){
    float s = em[tid] + be3[tid];
    for (int k=0;k<100;++k) s = fmaf(em2[k], we3[k*10+tid], s);
    em3[tid] = s;
    e3s[tid] = s;
  }
  __syncthreads();
  // embedding channels are spatially constant: mean = value, std = 0 -> rstd = 1/1e-3
  for (int idx=tid; idx<NS*10; idx+=256){
    int n = idx/10, j = idx - n*10;
    stats1[(n*32+22+j)*2+0] = e3s[j];
    stats1[(n*32+22+j)*2+1] = 1000.0f;
  }
}

// ---------------------------------------------------------------- one-sided Jacobi on A+sigma*I
// ONE WAVE per matrix (64-thread block). Lane j owns column j in registers
// (statically indexed) and mirrors it in LDS at stride JCOL=68 floats.
// Partner column fetched with 16 ds_read_b128 (1 KB/instr, ~85 B/cyc) instead
// of 64 ds_bpermute (256 B/instr, ~33 B/cyc) -- the r6 LDS pipe bottleneck.
// Write-back is per-lane predicated on rotation, so converged rounds cost
// only the read half. Single-wave execution => reads of round r always
// precede writes of round r (program order); __syncthreads (cheap for one
// wave) orders writes(r) vs reads(r+1).
__global__ __launch_bounds__(64, 1) void k_jacobi(const float* __restrict__ x,
                                                  float* __restrict__ Wg,
                                                  float* __restrict__ nrm2g,
                                                  float* __restrict__ sigg){
  __shared__ alignas(16) float col[64*JCOL];
  __shared__ float nr[64];
  const int lane = threadIdx.x;
  const int b = blockIdx.x;
  const float* mat = x + (size_t)b*NPOS;
  float a[64];
  float rsum = 0.f;
  #pragma unroll
  for (int i=0;i<64;++i){
    a[i] = 0.5f*(mat[(i<<6)+lane] + mat[(lane<<6)+i]);
    rsum += fabsf(a[i]);
  }
  // Gershgorin bound: sigma = max_i sum_j |A_ij| + 1  =>  A+sigma*I SPD
  #pragma unroll
  for (int off=1; off<64; off<<=1) rsum = fmaxf(rsum, __shfl_xor(rsum, off, 64));
  const float sigma = rsum + 1.0f;
  #pragma unroll
  for (int i=0;i<64;++i) a[i] += (i==lane) ? sigma : 0.0f;   // STATIC index

  float4* mc = (float4*)(col + lane*JCOL);
  #pragma unroll
  for (int q=0;q<16;++q){
    float4 v; v.x=a[4*q+0]; v.y=a[4*q+1]; v.z=a[4*q+2]; v.w=a[4*q+3];
    mc[q] = v;
  }
  float own = 0.f;
  #pragma unroll
  for (int i=0;i<64;++i) own = fmaf(a[i], a[i], own);
  nr[lane] = own;
  __syncthreads();

  #pragma unroll 1
  for (int sw=0; sw<NSWEEP; ++sw){
    own = 0.f;                                  // exact norm refresh per sweep
    #pragma unroll
    for (int i=0;i<64;++i) own = fmaf(a[i], a[i], own);
    nr[lane] = own;
    __syncthreads();
    int nrot = 0;
    #pragma unroll 1
    for (int m=1; m<64; ++m){
      const int p = lane ^ m;
      const float4* pc = (const float4*)(col + p*JCOL);
      float t[64];
      float d = 0.f;
      #pragma unroll
      for (int q=0;q<16;++q){
        float4 v = pc[q];
        t[4*q+0]=v.x; t[4*q+1]=v.y; t[4*q+2]=v.z; t[4*q+3]=v.w;
        d = fmaf(a[4*q+0], v.x, d);
        d = fmaf(a[4*q+1], v.y, d);
        d = fmaf(a[4*q+2], v.z, d);
        d = fmaf(a[4*q+3], v.w, d);
      }
      float oth = nr[p];
      bool rot = (d*d > 1e-14f*own*oth);
      if (__any(rot)){
        ++nrot;
        float tau = (oth - own)/(2.0f*d);
        float tt  = copysignf(1.0f, tau)/(fabsf(tau) + sqrtf(fmaf(tau,tau,1.0f)));
        float c   = 1.0f/sqrtf(fmaf(tt,tt,1.0f));
        float s   = tt*c;
        if (!rot){ c = 1.0f; s = 0.0f; tt = 0.0f; }   // also kills 0/0 NaN
        own = fmaf(-tt, d, own);
        float ns = -s;
        #pragma unroll
        for (int i=0;i<64;++i) a[i] = fmaf(ns, t[i], c*a[i]);
        if (rot){                       // only rotated columns rewrite their mirror
          #pragma unroll
          for (int q=0;q<16;++q){
            float4 v; v.x=a[4*q+0]; v.y=a[4*q+1]; v.z=a[4*q+2]; v.w=a[4*q+3];
            mc[q] = v;
          }
          nr[lane] = own;
        }
        __syncthreads();                // wave-uniform (block == one wave)
      }
    }
    if (nrot <= 2) break;   // near-converged: skip the pure-verification sweep
  }
  float nrm = 0.f;
  #pragma unroll
  for (int i=0;i<64;++i) nrm = fmaf(a[i],a[i],nrm);
  float* wp = Wg + (size_t)b*NPOS;
  #pragma unroll
  for (int i=0;i<64;++i) wp[(i<<6)+lane] = a[i];   // W row-major, coalesced
  nrm2g[(b<<6)+lane] = nrm;
  if (lane == 0) sigg[b] = sigma;
}

// ---------------------------------------------------------------- L = W diag(g/||w||^2) W^T (+ fused channel stats)
#define VP 68   // stride for b128 broadcast rows
#define WP 65   // stride for lane-varying b32 reads (2-way, free)
__global__ __launch_bounds__(256) void k_logm(float* __restrict__ WL,
                                              const float* __restrict__ nrm2g,
                                              const float* __restrict__ sigg,
                                              float* __restrict__ stats1){
  __shared__ alignas(16) float Vr[64*VP];
  __shared__ float Wr[64*WP];
  __shared__ float sc[64];
  __shared__ float red[4][2];
  const int b = blockIdx.x, tid = threadIdx.x;
  float* base = WL + (size_t)b*NPOS;
  if (tid < 64){
    float n2  = nrm2g[(b<<6)+tid];
    float lam = sqrtf(n2) - sigg[b];
    float g   = logf(fmaxf(lam, 1e-4f));
    sc[tid]   = g / n2;
  }
  __syncthreads();
  for (int idx=tid; idx<NPOS; idx+=256){
    int i = idx>>6, j = idx&63;
    float vv = base[idx];
    Vr[i*VP+j] = vv;
    Wr[i*WP+j] = sc[j]*vv;
  }
  __syncthreads();
  float s1 = 0.f, s2 = 0.f;
  for (int idx=tid; idx<NPOS; idx+=256){
    int i = idx>>6, k = idx&63;            // i wave-uniform, k = lane
    const float4* vrow = (const float4*)&Vr[i*VP];
    const float*  wrow = &Wr[k*WP];
    float4 acc = {0.f,0.f,0.f,0.f};
    #pragma unroll
    for (int j=0;j<16;++j){
      float4 a4 = vrow[j];                 // broadcast (same addr all lanes)
      acc.x = fmaf(a4.x, wrow[4*j+0], acc.x);
      acc.y = fmaf(a4.y, wrow[4*j+1], acc.y);
      acc.z = fmaf(a4.z, wrow[4*j+2], acc.z);
      acc.w = fmaf(a4.w, wrow[4*j+3], acc.w);
    }
    float L = (acc.x+acc.y)+(acc.z+acc.w);
    base[idx] = L;                          // overwrite W with L
    s1 += L; s2 = fmaf(L, L, s2);
  }
  for (int off=32; off; off>>=1){ s1 += __shfl_down(s1,off,64); s2 += __shfl_down(s2,off,64); }
  const int w = tid>>6, lane = tid&63;
  if (lane == 0){ red[w][0] = s1; red[w][1] = s2; }
  __syncthreads();
  if (tid == 0){
    s1 = red[0][0]+red[1][0]+red[2][0]+red[3][0];
    s2 = red[0][1]+red[1][1]+red[2][1]+red[3][1];
    float mean = s1*(1.0f/4096.0f);
    float var  = s2*(1.0f/4096.0f) - mean*mean;
    float sd   = sqrtf(fmaxf(var, 0.f));
    int n = b/CC, ch = b - n*CC;
    stats1[(n*32+ch)*2+0] = mean;
    stats1[(n*32+ch)*2+1] = 1.0f/fmaxf(sd, 1e-3f);
  }
}

// ---------------------------------------------------------------- pass 1: h2 stats
// Dynamic-j operands live in a per-thread LDS slot so the j-loops stay ROLLED
// while register accumulators t[k]/eu[k] stay STATIC (kills the r5 spill).
__global__ __launch_bounds__(256) void k_pass1(const float* __restrict__ logT,
    const float* __restrict__ em3, const float* __restrict__ stats1,
    const float* __restrict__ w2, const float* __restrict__ b2,
    const float* __restrict__ w3, const float* __restrict__ b3,
    float* __restrict__ s2raw){
  const int n = blockIdx.x;
  const int tid = threadIdx.x;
  const int pp = (blockIdx.y<<8) + tid;
  __shared__ alignas(16) float w2s[1024];
  __shared__ alignas(16) float w3s[1024];
  __shared__ float b2s[32], b3s[32], ms[32], rs[32], e3[10];
  __shared__ float eus[256*EUP];
  __shared__ float redp[4][64];
  for (int i=tid;i<1024;i+=256){ w2s[i]=w2[i]; w3s[i]=w3[i]; }
  if (tid<32){ b2s[tid]=b2[tid]; b3s[tid]=b3[tid];
    ms[tid]=stats1[(n*32+tid)*2]; rs[tid]=stats1[(n*32+tid)*2+1]; }
  if (tid<10) e3[tid]=em3[tid];
  __syncthreads();
  float eu[32], t[32];
  float* myeu = eus + tid*EUP;
  const float* base = logT + (size_t)n*CC*NPOS + pp;
  #pragma unroll
  for (int c=0;c<22;++c) eu[c] = base[c*NPOS];
  #pragma unroll
  for (int c=0;c<10;++c) eu[22+c] = e3[c];
  #pragma unroll
  for (int j=0;j<32;++j) myeu[j] = (eu[j]-ms[j])*rs[j];
  #pragma unroll
  for (int k=0;k<32;++k) t[k] = b2s[k];
  #pragma unroll 1
  for (int j=0;j<32;++j){
    float nj = myeu[j];
    const float4* wr = (const float4*)(w2s + (j<<5));
    #pragma unroll
    for (int q=0;q<8;++q){
      float4 w4 = wr[q];
      t[4*q+0] = fmaf(nj, w4.x, t[4*q+0]);
      t[4*q+1] = fmaf(nj, w4.y, t[4*q+1]);
      t[4*q+2] = fmaf(nj, w4.z, t[4*q+2]);
      t[4*q+3] = fmaf(nj, w4.w, t[4*q+3]);
    }
  }
  #pragma unroll
  for (int k=0;k<32;++k) myeu[k] = fmaxf(t[k], 0.f);
  #pragma unroll
  for (int k=0;k<32;++k) eu[k] += b3s[k];
  #pragma unroll 1
  for (int j=0;j<32;++j){
    float tj = myeu[j];
    const float4* wr = (const float4*)(w3s + (j<<5));
    #pragma unroll
    for (int q=0;q<8;++q){
      float4 w4 = wr[q];
      eu[4*q+0] = fmaf(tj, w4.x, eu[4*q+0]);
      eu[4*q+1] = fmaf(tj, w4.y, eu[4*q+1]);
      eu[4*q+2] = fmaf(tj, w4.z, eu[4*q+2]);
      eu[4*q+3] = fmaf(tj, w4.w, eu[4*q+3]);
    }
  }
  const int w = tid>>6, lane = tid&63;
  #pragma unroll
  for (int k=0;k<32;++k){
    float v = eu[k], v2 = eu[k]*eu[k];
    for (int off=32; off; off>>=1){ v += __shfl_down(v,off,64); v2 += __shfl_down(v2,off,64); }
    if (lane == 0){ redp[w][2*k] = v; redp[w][2*k+1] = v2; }
  }
  __syncthreads();
  if (tid < 64){
    float v = redp[0][tid]+redp[1][tid]+redp[2][tid]+redp[3][tid];
    atomicAdd(&s2raw[(n<<6)+tid], v);
  }
}

// ---------------------------------------------------------------- finalize h2 stats
__global__ void k_fin2(const float* __restrict__ s2raw, float* __restrict__ stats2){
  int i = blockIdx.x*256 + threadIdx.x;
  if (i < NS*32){
    float s = s2raw[2*i], sq = s2raw[2*i+1];
    float mean = s*(1.0f/4096.0f);
    float var  = sq*(1.0f/4096.0f) - mean*mean;
    float sd   = sqrtf(fmaxf(var, 0.f));
    stats2[2*i]   = mean;
    stats2[2*i+1] = 1.0f/fmaxf(sd, 1e-3f);
  }
}

// ---------------------------------------------------------------- pass 2: h3 accumulation (same rolled-j structure)
__global__ __launch_bounds__(256) void k_pass2(const float* __restrict__ logT,
    const float* __restrict__ em3, const float* __restrict__ stats1, const float* __restrict__ stats2,
    const float* __restrict__ w2, const float* __restrict__ b2,
    const float* __restrict__ w3, const float* __restrict__ b3,
    const float* __restrict__ w4, const float* __restrict__ b4,
    const float* __restrict__ w5, const float* __restrict__ b5,
    float* __restrict__ cov3){
  const int n = blockIdx.x;
  const int tid = threadIdx.x;
  const int pp = (blockIdx.y<<8) + tid;
  __shared__ alignas(16) float w2s[1024];
  __shared__ alignas(16) float w3s[1024];
  __shared__ alignas(16) float w4s[1024];
  __shared__ alignas(16) float w5s[1024];
  __shared__ float b2s[32], b3s[32], b4s[32], b5s[32];
  __shared__ float m1[32], r1[32], m2[32], r2[32], e3[10];
  __shared__ float eus[256*EUP];
  __shared__ float redp[4][32];
  for (int i=tid;i<1024;i+=256){ w2s[i]=w2[i]; w3s[i]=w3[i]; w4s[i]=w4[i]; w5s[i]=w5[i]; }
  if (tid<32){ b2s[tid]=b2[tid]; b3s[tid]=b3[tid]; b4s[tid]=b4[tid]; b5s[tid]=b5[tid];
    m1[tid]=stats1[(n*32+tid)*2]; r1[tid]=stats1[(n*32+tid)*2+1];
    m2[tid]=stats2[(n*32+tid)*2]; r2[tid]=stats2[(n*32+tid)*2+1]; }
  if (tid<10) e3[tid]=em3[tid];
  __syncthreads();
  float eu[32], t[32];
  float* myeu = eus + tid*EUP;
  const float* base = logT + (size_t)n*CC*NPOS + pp;
  #pragma unroll
  for (int c=0;c<22;++c) eu[c] = base[c*NPOS];
  #pragma unroll
  for (int c=0;c<10;++c) eu[22+c] = e3[c];
  // --- block 1 ---
  #pragma unroll
  for (int j=0;j<32;++j) myeu[j] = (eu[j]-m1[j])*r1[j];
  #pragma unroll
  for (int k=0;k<32;++k) t[k] = b2s[k];
  #pragma unroll 1
  for (int j=0;j<32;++j){
    float nj = myeu[j];
    const float4* wr = (const float4*)(w2s + (j<<5));
    #pragma unroll
    for (int q=0;q<8;++q){
      float4 w4v = wr[q];
      t[4*q+0] = fmaf(nj, w4v.x, t[4*q+0]);
      t[4*q+1] = fmaf(nj, w4v.y, t[4*q+1]);
      t[4*q+2] = fmaf(nj, w4v.z, t[4*q+2]);
      t[4*q+3] = fmaf(nj, w4v.w, t[4*q+3]);
    }
  }
  #pragma unroll
  for (int k=0;k<32;++k) myeu[k] = fmaxf(t[k], 0.f);
  #pragma unroll
  for (int k=0;k<32;++k) eu[k] += b3s[k];
  #pragma unroll 1
  for (int j=0;j<32;++j){
    float tj = myeu[j];
    const float4* wr = (const float4*)(w3s + (j<<5));
    #pragma unroll
    for (int q=0;q<8;++q){
      float4 w4v = wr[q];
      eu[4*q+0] = fmaf(tj, w4v.x, eu[4*q+0]);
      eu[4*q+1] = fmaf(tj, w4v.y, eu[4*q+1]);
      eu[4*q+2] = fmaf(tj, w4v.z, eu[4*q+2]);
      eu[4*q+3] = fmaf(tj, w4v.w, eu[4*q+3]);
    }
  }
  // --- block 2 ---
  #pragma unroll
  for (int j=0;j<32;++j) myeu[j] = (eu[j]-m2[j])*r2[j];
  #pragma unroll
  for (int k=0;k<32;++k) t[k] = b4s[k];
  #pragma unroll 1
  for (int j=0;j<32;++j){
    float nj = myeu[j];
    const float4* wr = (const float4*)(w4s + (j<<5));
    #pragma unroll
    for (int q=0;q<8;++q){
      float4 w4v = wr[q];
      t[4*q+0] = fmaf(nj, w4v.x, t[4*q+0]);
      t[4*q+1] = fmaf(nj, w4v.y, t[4*q+1]);
      t[4*q+2] = fmaf(nj, w4v.z, t[4*q+2]);
      t[4*q+3] = fmaf(nj, w4v.w, t[4*q+3]);
    }
  }
  #pragma unroll
  for (int k=0;k<32;++k) myeu[k] = fmaxf(t[k], 0.f);
  #pragma unroll
  for (int k=0;k<32;++k) eu[k] += b5s[k];
  #pragma unroll 1
  for (int j=0;j<32;++j){
    float tj = myeu[j];
    const float4* wr = (const float4*)(w5s + (j<<5));
    #pragma unroll
    for (int q=0;q<8;++q){
      float4 w4v = wr[q];
      eu[4*q+0] = fmaf(tj, w4v.x, eu[4*q+0]);
      eu[4*q+1] = fmaf(tj, w4v.y, eu[4*q+1]);
      eu[4*q+2] = fmaf(tj, w4v.z, eu[4*q+2]);
      eu[4*q+3] = fmaf(tj, w4v.w, eu[4*q+3]);
    }
  }
  const int w = tid>>6, lane = tid&63;
  #pragma unroll
  for (int k=0;k<32;++k){
    float v = eu[k];
    for (int off=32; off; off>>=1) v += __shfl_down(v,off,64);
    if (lane == 0) redp[w][k] = v;
  }
  __syncthreads();
  if (tid < 32){
    float v = redp[0][tid]+redp[1][tid]+redp[2][tid]+redp[3][tid];
    atomicAdd(&cov3[(n<<5)+tid], v);
  }
}

// ---------------------------------------------------------------- head: mean -> matmul -> softmax
__global__ void k_out(const float* __restrict__ cov3, const float* __restrict__ w,
                      float* __restrict__ out){
  __shared__ float wsm[224];
  const int tid = threadIdx.x;
  if (tid < 224) wsm[tid] = w[tid];
  __syncthreads();
  const int n = tid;
  float l[7];
  #pragma unroll
  for (int c=0;c<7;++c) l[c] = 0.f;
  #pragma unroll
  for (int ch=0;ch<32;++ch){
    float v = cov3[(n<<5)+ch]*(1.0f/4096.0f);
    #pragma unroll
    for (int c=0;c<7;++c) l[c] = fmaf(v, wsm[ch*7+c], l[c]);
  }
  float mx = l[0];
  #pragma unroll
  for (int c=1;c<7;++c) mx = fmaxf(mx, l[c]);
  float ssum = 0.f;
  #pragma unroll
  for (int c=0;c<7;++c){ l[c] = expf(l[c]-mx); ssum += l[c]; }
  float inv = 1.0f/ssum;
  #pragma unroll
  for (int c=0;c<7;++c) out[n*7+c] = l[c]*inv;
}

// ----------------------------------------------------------------
extern "C" void kernel_launch(void* const* d_in, const int* in_sizes, int n_in,
                              void* d_out, int out_size, void* d_ws, size_t ws_size,
                              hipStream_t stream){
  const float* x   = (const float*)d_in[0];
  const int*   Mp  = (const int*)  d_in[1];
  const float* w   = (const float*)d_in[2];
  const float* w2  = (const float*)d_in[3];
  const float* b2  = (const float*)d_in[4];
  const float* w3  = (const float*)d_in[5];
  const float* b3  = (const float*)d_in[6];
  const float* w4  = (const float*)d_in[7];
  const float* b4  = (const float*)d_in[8];
  const float* w5  = (const float*)d_in[9];
  const float* b5  = (const float*)d_in[10];
  const float* we1 = (const float*)d_in[11];
  const float* be1 = (const float*)d_in[12];
  const float* we2 = (const float*)d_in[13];
  const float* be2 = (const float*)d_in[14];
  const float* we3 = (const float*)d_in[15];
  const float* be3 = (const float*)d_in[16];
  const float* lng = (const float*)d_in[17];
  const float* lnb = (const float*)d_in[18];

  float* wsf    = (float*)d_ws;
  float* WL     = wsf;                           // [NMAT,4096] W then L in place (92.3 MB)
  float* nrm2g  = WL + (size_t)NMAT*NPOS;        // [NMAT,64]
  float* sigg   = nrm2g + (size_t)NMAT*64;       // [NMAT]
  float* em3    = sigg + NMAT;                   // 16
  float* stats1 = em3 + 16;                      // [N,32,2]
  float* s2raw  = stats1 + NS*64;                // [N,32,2] accum (zeroed)
  float* cov3   = s2raw + NS*64;                 // [N,32]   accum (zeroed)
  float* stats2 = cov3 + NS*32;                  // [N,32,2]

  hipMemsetAsync(s2raw, 0, (size_t)(NS*64 + NS*32)*sizeof(float), stream);

  k_embed <<<1, 256, 0, stream>>>(we1,be1,we2,be2,we3,be3,lng,lnb,Mp,em3,stats1);
  k_jacobi<<<NMAT, 64, 0, stream>>>(x, WL, nrm2g, sigg);
  k_logm  <<<NMAT, 256, 0, stream>>>(WL, nrm2g, sigg, stats1);
  k_pass1 <<<dim3(NS,16), 256, 0, stream>>>(WL, em3, stats1, w2,b2,w3,b3, s2raw);
  k_fin2  <<<(NS*32+255)/256, 256, 0, stream>>>(s2raw, stats2);
  k_pass2 <<<dim3(NS,16), 256, 0, stream>>>(WL, em3, stats1, stats2,
                                            w2,b2,w3,b3,w4,b4,w5,b5, cov3);
  k_out   <<<1, 256, 0, stream>>>(cov3, w, (float*)d_out);
}

// Round 8
// 2355.217 us; speedup vs baseline: 5.4070x; 1.0256x over previous
//
#include <hip/hip_runtime.h>
#include <math.h>

// Problem constants
#define NS 256        // batch N
#define CC 22         // channels c
#define DD 64         // matrix dim d
#define NPOS 4096     // d*d spatial positions
#define NMAT (NS*CC)  // 5632 matrices
#define NSWEEP 10     // one-sided Jacobi sweeps (63 XOR rounds each; early-exit on convergence)
#define EUP 33        // per-thread LDS slot stride: (tid*33+j)%32 -> 2-way (free)
#define JCOL 68       // jacobi LDS column stride (floats): 16B-aligned
#define JTH 2.5e-13f  // rotation threshold: d^2 > JTH*|p|^2*|q|^2  (rel off-diag 5e-7)

// ---------------------------------------------------------------- embedding MLP (+ constant-channel stats)
__global__ void k_embed(const float* __restrict__ we1, const float* __restrict__ be1,
                        const float* __restrict__ we2, const float* __restrict__ be2,
                        const float* __restrict__ we3, const float* __restrict__ be3,
                        const float* __restrict__ lng, const float* __restrict__ lnb,
                        const int* __restrict__ Mp, float* __restrict__ em3,
                        float* __restrict__ stats1){
  __shared__ float em[10], emln[10], em2[100], e3s[10];
  int tid = threadIdx.x;
  if (tid == 0){
    float md0 = (float)Mp[0] / 500.0f;
    float md1 = 64.0f / 100.0f;
    float mu = 0.f;
    for (int j=0;j<10;++j){ em[j] = md0*we1[j] + md1*we1[10+j] + be1[j]; mu += em[j]; }
    mu *= 0.1f;
    float var = 0.f;
    for (int j=0;j<10;++j){ float d = em[j]-mu; var += d*d; }
    var *= 0.1f;
    float rs = 1.0f/sqrtf(var + 1e-3f);
    for (int j=0;j<10;++j) emln[j] = (em[j]-mu)*rs*lng[j] + lnb[j];
  }
  __syncthreads();
  if (tid < 100){
    float s = be2[tid];
    for (int j=0;j<10;++j) s = fmaf(emln[j], we2[j*100+tid], s);
    em2[tid] = fmaxf(s, 0.f);
  }
  __syncthreads();
  if (tid < 10){
    float s = em[tid] + be3[tid];
    for (int k=0;k<100;++k) s = fmaf(em2[k], we3[k*10+tid], s);
    em3[tid] = s;
    e3s[tid] = s;
  }
  __syncthreads();
  // embedding channels are spatially constant: mean = value, std = 0 -> rstd = 1/1e-3
  for (int idx=tid; idx<NS*10; idx+=256){
    int n = idx/10, j = idx - n*10;
    stats1[(n*32+22+j)*2+0] = e3s[j];
    stats1[(n*32+22+j)*2+1] = 1000.0f;
  }
}

// ---------------------------------------------------------------- one-sided Jacobi on A+sigma*I
// ONE WAVE per matrix. Lane j owns column j in registers (static indices) and
// mirrors it in LDS (stride JCOL). Partner column: 16 ds_read_b128, kept LIVE
// in t[64] — rotation applied UNCONDITIONALLY (c=1,s=0 identity for converged
// lanes) so t's live range crosses no branch and the compiler doesn't
// rematerialize it from LDS (r7: VGPR=76 + 16 redundant b128/round).
// Write-back + nr update predicated on rot; sync only when any lane rotated.
__global__ __launch_bounds__(64, 1) void k_jacobi(const float* __restrict__ x,
                                                  float* __restrict__ Wg,
                                                  float* __restrict__ nrm2g,
                                                  float* __restrict__ sigg){
  __shared__ alignas(16) float col[64*JCOL];
  __shared__ float nr[64];
  const int lane = threadIdx.x;
  const int b = blockIdx.x;
  const float* mat = x + (size_t)b*NPOS;
  float a[64];
  float rsum = 0.f;
  #pragma unroll
  for (int i=0;i<64;++i){
    a[i] = 0.5f*(mat[(i<<6)+lane] + mat[(lane<<6)+i]);
    rsum += fabsf(a[i]);
  }
  // Gershgorin bound: sigma = max_i sum_j |A_ij| + 1  =>  A+sigma*I SPD
  #pragma unroll
  for (int off=1; off<64; off<<=1) rsum = fmaxf(rsum, __shfl_xor(rsum, off, 64));
  const float sigma = rsum + 1.0f;
  #pragma unroll
  for (int i=0;i<64;++i) a[i] += (i==lane) ? sigma : 0.0f;   // STATIC index

  float4* mc = (float4*)(col + lane*JCOL);
  #pragma unroll
  for (int q=0;q<16;++q){
    float4 v; v.x=a[4*q+0]; v.y=a[4*q+1]; v.z=a[4*q+2]; v.w=a[4*q+3];
    mc[q] = v;
  }
  float own = 0.f;
  #pragma unroll
  for (int i=0;i<64;++i) own = fmaf(a[i], a[i], own);
  nr[lane] = own;
  __syncthreads();

  #pragma unroll 1
  for (int sw=0; sw<NSWEEP; ++sw){
    own = 0.f;                                  // exact norm refresh per sweep
    #pragma unroll
    for (int i=0;i<64;++i) own = fmaf(a[i], a[i], own);
    nr[lane] = own;
    __syncthreads();
    int nrot = 0;
    #pragma unroll 1
    for (int m=1; m<64; ++m){
      const int p = lane ^ m;
      const float4* pc = (const float4*)(col + p*JCOL);
      float t[64];
      float d = 0.f;
      #pragma unroll
      for (int q=0;q<16;++q){
        float4 v = pc[q];
        t[4*q+0]=v.x; t[4*q+1]=v.y; t[4*q+2]=v.z; t[4*q+3]=v.w;
        d = fmaf(a[4*q+0], v.x, d);
        d = fmaf(a[4*q+1], v.y, d);
        d = fmaf(a[4*q+2], v.z, d);
        d = fmaf(a[4*q+3], v.w, d);
      }
      float oth = nr[p];
      bool rot = (d*d > JTH*own*oth);
      // angle (computed for all lanes; forced to identity when !rot)
      float tau = (oth - own)/(2.0f*d);
      float tt  = copysignf(1.0f, tau)/(fabsf(tau) + sqrtf(fmaf(tau,tau,1.0f)));
      float c   = 1.0f/sqrtf(fmaf(tt,tt,1.0f));
      float s   = tt*c;
      if (!rot){ c = 1.0f; s = 0.0f; tt = 0.0f; }   // identity; also kills 0/0 NaN
      own = fmaf(-tt, d, own);
      float ns = -s;
      #pragma unroll
      for (int i=0;i<64;++i) a[i] = fmaf(ns, t[i], c*a[i]);   // unconditional
      if (__any(rot)){
        ++nrot;
        if (rot){                       // only rotated columns rewrite their mirror
          #pragma unroll
          for (int q=0;q<16;++q){
            float4 v; v.x=a[4*q+0]; v.y=a[4*q+1]; v.z=a[4*q+2]; v.w=a[4*q+3];
            mc[q] = v;
          }
          nr[lane] = own;
        }
        __syncthreads();                // wave-uniform (block == one wave)
      }
    }
    if (nrot <= 2) break;   // near-converged: skip the pure-verification sweep
  }
  float nrm = 0.f;
  #pragma unroll
  for (int i=0;i<64;++i) nrm = fmaf(a[i],a[i],nrm);
  float* wp = Wg + (size_t)b*NPOS;
  #pragma unroll
  for (int i=0;i<64;++i) wp[(i<<6)+lane] = a[i];   // W row-major, coalesced
  nrm2g[(b<<6)+lane] = nrm;
  if (lane == 0) sigg[b] = sigma;
}

// ---------------------------------------------------------------- L = W diag(g/||w||^2) W^T (+ fused channel stats)
#define VP 68   // stride for b128 broadcast rows
#define WP 65   // stride for lane-varying b32 reads (2-way, free)
__global__ __launch_bounds__(256) void k_logm(float* __restrict__ WL,
                                              const float* __restrict__ nrm2g,
                                              const float* __restrict__ sigg,
                                              float* __restrict__ stats1){
  __shared__ alignas(16) float Vr[64*VP];
  __shared__ float Wr[64*WP];
  __shared__ float sc[64];
  __shared__ float red[4][2];
  const int b = blockIdx.x, tid = threadIdx.x;
  float* base = WL + (size_t)b*NPOS;
  if (tid < 64){
    float n2  = nrm2g[(b<<6)+tid];
    float lam = sqrtf(n2) - sigg[b];
    float g   = logf(fmaxf(lam, 1e-4f));
    sc[tid]   = g / n2;
  }
  __syncthreads();
  for (int idx=tid; idx<NPOS; idx+=256){
    int i = idx>>6, j = idx&63;
    float vv = base[idx];
    Vr[i*VP+j] = vv;
    Wr[i*WP+j] = sc[j]*vv;
  }
  __syncthreads();
  float s1 = 0.f, s2 = 0.f;
  for (int idx=tid; idx<NPOS; idx+=256){
    int i = idx>>6, k = idx&63;            // i wave-uniform, k = lane
    const float4* vrow = (const float4*)&Vr[i*VP];
    const float*  wrow = &Wr[k*WP];
    float4 acc = {0.f,0.f,0.f,0.f};
    #pragma unroll
    for (int j=0;j<16;++j){
      float4 a4 = vrow[j];                 // broadcast (same addr all lanes)
      acc.x = fmaf(a4.x, wrow[4*j+0], acc.x);
      acc.y = fmaf(a4.y, wrow[4*j+1], acc.y);
      acc.z = fmaf(a4.z, wrow[4*j+2], acc.z);
      acc.w = fmaf(a4.w, wrow[4*j+3], acc.w);
    }
    float L = (acc.x+acc.y)+(acc.z+acc.w);
    base[idx] = L;                          // overwrite W with L
    s1 += L; s2 = fmaf(L, L, s2);
  }
  for (int off=32; off; off>>=1){ s1 += __shfl_down(s1,off,64); s2 += __shfl_down(s2,off,64); }
  const int w = tid>>6, lane = tid&63;
  if (lane == 0){ red[w][0] = s1; red[w][1] = s2; }
  __syncthreads();
  if (tid == 0){
    s1 = red[0][0]+red[1][0]+red[2][0]+red[3][0];
    s2 = red[0][1]+red[1][1]+red[2][1]+red[3][1];
    float mean = s1*(1.0f/4096.0f);
    float var  = s2*(1.0f/4096.0f) - mean*mean;
    float sd   = sqrtf(fmaxf(var, 0.f));
    int n = b/CC, ch = b - n*CC;
    stats1[(n*32+ch)*2+0] = mean;
    stats1[(n*32+ch)*2+1] = 1.0f/fmaxf(sd, 1e-3f);
  }
}

// ---------------------------------------------------------------- pass 1: h2 stats
// Dynamic-j operands live in a per-thread LDS slot so the j-loops stay ROLLED
// while register accumulators t[k]/eu[k] stay STATIC (kills the r5 spill).
__global__ __launch_bounds__(256) void k_pass1(const float* __restrict__ logT,
    const float* __restrict__ em3, const float* __restrict__ stats1,
    const float* __restrict__ w2, const float* __restrict__ b2,
    const float* __restrict__ w3, const float* __restrict__ b3,
    float* __restrict__ s2raw){
  const int n = blockIdx.x;
  const int tid = threadIdx.x;
  const int pp = (blockIdx.y<<8) + tid;
  __shared__ alignas(16) float w2s[1024];
  __shared__ alignas(16) float w3s[1024];
  __shared__ float b2s[32], b3s[32], ms[32], rs[32], e3[10];
  __shared__ float eus[256*EUP];
  __shared__ float redp[4][64];
  for (int i=tid;i<1024;i+=256){ w2s[i]=w2[i]; w3s[i]=w3[i]; }
  if (tid<32){ b2s[tid]=b2[tid]; b3s[tid]=b3[tid];
    ms[tid]=stats1[(n*32+tid)*2]; rs[tid]=stats1[(n*32+tid)*2+1]; }
  if (tid<10) e3[tid]=em3[tid];
  __syncthreads();
  float eu[32], t[32];
  float* myeu = eus + tid*EUP;
  const float* base = logT + (size_t)n*CC*NPOS + pp;
  #pragma unroll
  for (int c=0;c<22;++c) eu[c] = base[c*NPOS];
  #pragma unroll
  for (int c=0;c<10;++c) eu[22+c] = e3[c];
  #pragma unroll
  for (int j=0;j<32;++j) myeu[j] = (eu[j]-ms[j])*rs[j];
  #pragma unroll
  for (int k=0;k<32;++k) t[k] = b2s[k];
  #pragma unroll 1
  for (int j=0;j<32;++j){
    float nj = myeu[j];
    const float4* wr = (const float4*)(w2s + (j<<5));
    #pragma unroll
    for (int q=0;q<8;++q){
      float4 w4 = wr[q];
      t[4*q+0] = fmaf(nj, w4.x, t[4*q+0]);
      t[4*q+1] = fmaf(nj, w4.y, t[4*q+1]);
      t[4*q+2] = fmaf(nj, w4.z, t[4*q+2]);
      t[4*q+3] = fmaf(nj, w4.w, t[4*q+3]);
    }
  }
  #pragma unroll
  for (int k=0;k<32;++k) myeu[k] = fmaxf(t[k], 0.f);
  #pragma unroll
  for (int k=0;k<32;++k) eu[k] += b3s[k];
  #pragma unroll 1
  for (int j=0;j<32;++j){
    float tj = myeu[j];
    const float4* wr = (const float4*)(w3s + (j<<5));
    #pragma unroll
    for (int q=0;q<8;++q){
      float4 w4 = wr[q];
      eu[4*q+0] = fmaf(tj, w4.x, eu[4*q+0]);
      eu[4*q+1] = fmaf(tj, w4.y, eu[4*q+1]);
      eu[4*q+2] = fmaf(tj, w4.z, eu[4*q+2]);
      eu[4*q+3] = fmaf(tj, w4.w, eu[4*q+3]);
    }
  }
  const int w = tid>>6, lane = tid&63;
  #pragma unroll
  for (int k=0;k<32;++k){
    float v = eu[k], v2 = eu[k]*eu[k];
    for (int off=32; off; off>>=1){ v += __shfl_down(v,off,64); v2 += __shfl_down(v2,off,64); }
    if (lane == 0){ redp[w][2*k] = v; redp[w][2*k+1] = v2; }
  }
  __syncthreads();
  if (tid < 64){
    float v = redp[0][tid]+redp[1][tid]+redp[2][tid]+redp[3][tid];
    atomicAdd(&s2raw[(n<<6)+tid], v);
  }
}

// ---------------------------------------------------------------- finalize h2 stats
__global__ void k_fin2(const float* __restrict__ s2raw, float* __restrict__ stats2){
  int i = blockIdx.x*256 + threadIdx.x;
  if (i < NS*32){
    float s = s2raw[2*i], sq = s2raw[2*i+1];
    float mean = s*(1.0f/4096.0f);
    float var  = sq*(1.0f/4096.0f) - mean*mean;
    float sd   = sqrtf(fmaxf(var, 0.f));
    stats2[2*i]   = mean;
    stats2[2*i+1] = 1.0f/fmaxf(sd, 1e-3f);
  }
}

// ---------------------------------------------------------------- pass 2: h3 accumulation (same rolled-j structure)
__global__ __launch_bounds__(256) void k_pass2(const float* __restrict__ logT,
    const float* __restrict__ em3, const float* __restrict__ stats1, const float* __restrict__ stats2,
    const float* __restrict__ w2, const float* __restrict__ b2,
    const float* __restrict__ w3, const float* __restrict__ b3,
    const float* __restrict__ w4, const float* __restrict__ b4,
    const float* __restrict__ w5, const float* __restrict__ b5,
    float* __restrict__ cov3){
  const int n = blockIdx.x;
  const int tid = threadIdx.x;
  const int pp = (blockIdx.y<<8) + tid;
  __shared__ alignas(16) float w2s[1024];
  __shared__ alignas(16) float w3s[1024];
  __shared__ alignas(16) float w4s[1024];
  __shared__ alignas(16) float w5s[1024];
  __shared__ float b2s[32], b3s[32], b4s[32], b5s[32];
  __shared__ float m1[32], r1[32], m2[32], r2[32], e3[10];
  __shared__ float eus[256*EUP];
  __shared__ float redp[4][32];
  for (int i=tid;i<1024;i+=256){ w2s[i]=w2[i]; w3s[i]=w3[i]; w4s[i]=w4[i]; w5s[i]=w5[i]; }
  if (tid<32){ b2s[tid]=b2[tid]; b3s[tid]=b3[tid]; b4s[tid]=b4[tid]; b5s[tid]=b5[tid];
    m1[tid]=stats1[(n*32+tid)*2]; r1[tid]=stats1[(n*32+tid)*2+1];
    m2[tid]=stats2[(n*32+tid)*2]; r2[tid]=stats2[(n*32+tid)*2+1]; }
  if (tid<10) e3[tid]=em3[tid];
  __syncthreads();
  float eu[32], t[32];
  float* myeu = eus + tid*EUP;
  const float* base = logT + (size_t)n*CC*NPOS + pp;
  #pragma unroll
  for (int c=0;c<22;++c) eu[c] = base[c*NPOS];
  #pragma unroll
  for (int c=0;c<10;++c) eu[22+c] = e3[c];
  // --- block 1 ---
  #pragma unroll
  for (int j=0;j<32;++j) myeu[j] = (eu[j]-m1[j])*r1[j];
  #pragma unroll
  for (int k=0;k<32;++k) t[k] = b2s[k];
  #pragma unroll 1
  for (int j=0;j<32;++j){
    float nj = myeu[j];
    const float4* wr = (const float4*)(w2s + (j<<5));
    #pragma unroll
    for (int q=0;q<8;++q){
      float4 w4v = wr[q];
      t[4*q+0] = fmaf(nj, w4v.x, t[4*q+0]);
      t[4*q+1] = fmaf(nj, w4v.y, t[4*q+1]);
      t[4*q+2] = fmaf(nj, w4v.z, t[4*q+2]);
      t[4*q+3] = fmaf(nj, w4v.w, t[4*q+3]);
    }
  }
  #pragma unroll
  for (int k=0;k<32;++k) myeu[k] = fmaxf(t[k], 0.f);
  #pragma unroll
  for (int k=0;k<32;++k) eu[k] += b3s[k];
  #pragma unroll 1
  for (int j=0;j<32;++j){
    float tj = myeu[j];
    const float4* wr = (const float4*)(w3s + (j<<5));
    #pragma unroll
    for (int q=0;q<8;++q){
      float4 w4v = wr[q];
      eu[4*q+0] = fmaf(tj, w4v.x, eu[4*q+0]);
      eu[4*q+1] = fmaf(tj, w4v.y, eu[4*q+1]);
      eu[4*q+2] = fmaf(tj, w4v.z, eu[4*q+2]);
      eu[4*q+3] = fmaf(tj, w4v.w, eu[4*q+3]);
    }
  }
  // --- block 2 ---
  #pragma unroll
  for (int j=0;j<32;++j) myeu[j] = (eu[j]-m2[j])*r2[j];
  #pragma unroll
  for (int k=0;k<32;++k) t[k] = b4s[k];
  #pragma unroll 1
  for (int j=0;j<32;++j){
    float nj = myeu[j];
    const float4* wr = (const float4*)(w4s + (j<<5));
    #pragma unroll
    for (int q=0;q<8;++q){
      float4 w4v = wr[q];
      t[4*q+0] = fmaf(nj, w4v.x, t[4*q+0]);
      t[4*q+1] = fmaf(nj, w4v.y, t[4*q+1]);
      t[4*q+2] = fmaf(nj, w4v.z, t[4*q+2]);
      t[4*q+3] = fmaf(nj, w4v.w, t[4*q+3]);
    }
  }
  #pragma unroll
  for (int k=0;k<32;++k) myeu[k] = fmaxf(t[k], 0.f);
  #pragma unroll
  for (int k=0;k<32;++k) eu[k] += b5s[k];
  #pragma unroll 1
  for (int j=0;j<32;++j){
    float tj = myeu[j];
    const float4* wr = (const float4*)(w5s + (j<<5));
    #pragma unroll
    for (int q=0;q<8;++q){
      float4 w4v = wr[q];
      eu[4*q+0] = fmaf(tj, w4v.x, eu[4*q+0]);
      eu[4*q+1] = fmaf(tj, w4v.y, eu[4*q+1]);
      eu[4*q+2] = fmaf(tj, w4v.z, eu[4*q+2]);
      eu[4*q+3] = fmaf(tj, w4v.w, eu[4*q+3]);
    }
  }
  const int w = tid>>6, lane = tid&63;
  #pragma unroll
  for (int k=0;k<32;++k){
    float v = eu[k];
    for (int off=32; off; off>>=1) v += __shfl_down(v,off,64);
    if (lane == 0) redp[w][k] = v;
  }
  __syncthreads();
  if (tid < 32){
    float v = redp[0][tid]+redp[1][tid]+redp[2][tid]+redp[3][tid];
    atomicAdd(&cov3[(n<<5)+tid], v);
  }
}

// ---------------------------------------------------------------- head: mean -> matmul -> softmax
__global__ void k_out(const float* __restrict__ cov3, const float* __restrict__ w,
                      float* __restrict__ out){
  __shared__ float wsm[224];
  const int tid = threadIdx.x;
  if (tid < 224) wsm[tid] = w[tid];
  __syncthreads();
  const int n = tid;
  float l[7];
  #pragma unroll
  for (int c=0;c<7;++c) l[c] = 0.f;
  #pragma unroll
  for (int ch=0;ch<32;++ch){
    float v = cov3[(n<<5)+ch]*(1.0f/4096.0f);
    #pragma unroll
    for (int c=0;c<7;++c) l[c] = fmaf(v, wsm[ch*7+c], l[c]);
  }
  float mx = l[0];
  #pragma unroll
  for (int c=1;c<7;++c) mx = fmaxf(mx, l[c]);
  float ssum = 0.f;
  #pragma unroll
  for (int c=0;c<7;++c){ l[c] = expf(l[c]-mx); ssum += l[c]; }
  float inv = 1.0f/ssum;
  #pragma unroll
  for (int c=0;c<7;++c) out[n*7+c] = l[c]*inv;
}

// ----------------------------------------------------------------
extern "C" void kernel_launch(void* const* d_in, const int* in_sizes, int n_in,
                              void* d_out, int out_size, void* d_ws, size_t ws_size,
                              hipStream_t stream){
  const float* x   = (const float*)d_in[0];
  const int*   Mp  = (const int*)  d_in[1];
  const float* w   = (const float*)d_in[2];
  const float* w2  = (const float*)d_in[3];
  const float* b2  = (const float*)d_in[4];
  const float* w3  = (const float*)d_in[5];
  const float* b3  = (const float*)d_in[6];
  const float* w4  = (const float*)d_in[7];
  const float* b4  = (const float*)d_in[8];
  const float* w5  = (const float*)d_in[9];
  const float* b5  = (const float*)d_in[10];
  const float* we1 = (const float*)d_in[11];
  const float* be1 = (const float*)d_in[12];
  const float* we2 = (const float*)d_in[13];
  const float* be2 = (const float*)d_in[14];
  const float* we3 = (const float*)d_in[15];
  const float* be3 = (const float*)d_in[16];
  const float* lng = (const float*)d_in[17];
  const float* lnb = (const float*)d_in[18];

  float* wsf    = (float*)d_ws;
  float* WL     = wsf;                           // [NMAT,4096] W then L in place (92.3 MB)
  float* nrm2g  = WL + (size_t)NMAT*NPOS;        // [NMAT,64]
  float* sigg   = nrm2g + (size_t)NMAT*64;       // [NMAT]
  float* em3    = sigg + NMAT;                   // 16
  float* stats1 = em3 + 16;                      // [N,32,2]
  float* s2raw  = stats1 + NS*64;                // [N,32,2] accum (zeroed)
  float* cov3   = s2raw + NS*64;                 // [N,32]   accum (zeroed)
  float* stats2 = cov3 + NS*32;                  // [N,32,2]

  hipMemsetAsync(s2raw, 0, (size_t)(NS*64 + NS*32)*sizeof(float), stream);

  k_embed <<<1, 256, 0, stream>>>(we1,be1,we2,be2,we3,be3,lng,lnb,Mp,em3,stats1);
  k_jacobi<<<NMAT, 64, 0, stream>>>(x, WL, nrm2g, sigg);
  k_logm  <<<NMAT, 256, 0, stream>>>(WL, nrm2g, sigg, stats1);
  k_pass1 <<<dim3(NS,16), 256, 0, stream>>>(WL, em3, stats1, w2,b2,w3,b3, s2raw);
  k_fin2  <<<(NS*32+255)/256, 256, 0, stream>>>(s2raw, stats2);
  k_pass2 <<<dim3(NS,16), 256, 0, stream>>>(WL, em3, stats1, stats2,
                                            w2,b2,w3,b3,w4,b4,w5,b5, cov3);
  k_out   <<<1, 256, 0, stream>>>(cov3, w, (float*)d_out);
}

// Round 9
// 2341.167 us; speedup vs baseline: 5.4394x; 1.0060x over previous
//
#include <hip/hip_runtime.h>
#include <math.h>

// Problem constants
#define NS 256        // batch N
#define CC 22         // channels c
#define DD 64         // matrix dim d
#define NPOS 4096     // d*d spatial positions
#define NMAT (NS*CC)  // 5632 matrices
#define NSWEEP 10     // one-sided Jacobi sweeps (63 XOR rounds each; early-exit on convergence)
#define EUP 33        // per-thread LDS slot stride: (tid*33+j)%32 -> 2-way (free)
#define JCOL 68       // jacobi LDS column stride (floats): 16B-aligned; 0 bank conflicts measured
#define JTH 2.5e-13f  // rotation threshold: d^2 > JTH*|p|^2*|q|^2  (rel off-diag 5e-7)

// ---------------------------------------------------------------- embedding MLP (+ constant-channel stats)
__global__ void k_embed(const float* __restrict__ we1, const float* __restrict__ be1,
                        const float* __restrict__ we2, const float* __restrict__ be2,
                        const float* __restrict__ we3, const float* __restrict__ be3,
                        const float* __restrict__ lng, const float* __restrict__ lnb,
                        const int* __restrict__ Mp, float* __restrict__ em3,
                        float* __restrict__ stats1){
  __shared__ float em[10], emln[10], em2[100], e3s[10];
  int tid = threadIdx.x;
  if (tid == 0){
    float md0 = (float)Mp[0] / 500.0f;
    float md1 = 64.0f / 100.0f;
    float mu = 0.f;
    for (int j=0;j<10;++j){ em[j] = md0*we1[j] + md1*we1[10+j] + be1[j]; mu += em[j]; }
    mu *= 0.1f;
    float var = 0.f;
    for (int j=0;j<10;++j){ float d = em[j]-mu; var += d*d; }
    var *= 0.1f;
    float rs = 1.0f/sqrtf(var + 1e-3f);
    for (int j=0;j<10;++j) emln[j] = (em[j]-mu)*rs*lng[j] + lnb[j];
  }
  __syncthreads();
  if (tid < 100){
    float s = be2[tid];
    for (int j=0;j<10;++j) s = fmaf(emln[j], we2[j*100+tid], s);
    em2[tid] = fmaxf(s, 0.f);
  }
  __syncthreads();
  if (tid < 10){
    float s = em[tid] + be3[tid];
    for (int k=0;k<100;++k) s = fmaf(em2[k], we3[k*10+tid], s);
    em3[tid] = s;
    e3s[tid] = s;
  }
  __syncthreads();
  // embedding channels are spatially constant: mean = value, std = 0 -> rstd = 1/1e-3
  for (int idx=tid; idx<NS*10; idx+=256){
    int n = idx/10, j = idx - n*10;
    stats1[(n*32+22+j)*2+0] = e3s[j];
    stats1[(n*32+22+j)*2+1] = 1000.0f;
  }
}

// ---------------------------------------------------------------- one-sided Jacobi on A+sigma*I
// ONE WAVE per matrix. Lane j owns column j in registers (static indices) and
// mirrors it in LDS (stride JCOL). Partner column: 16 ds_read_b128 into t[64].
// The asm memory clobber between the dot pass and the rotation makes LDS
// rematerialization of t UNSOUND, forcing the allocator to keep t in VGPRs
// (r7/r8: VGPR=76 => compiler re-read 16 b128/active round from LDS).
// LDS (17.9 KB) caps occupancy at 8 blocks/CU regardless, so the extra ~64
// VGPRs are free. Rotation applied unconditionally (identity when !rot);
// write-back + nr update predicated; sync only when any lane rotated.
__global__ __launch_bounds__(64, 1) void k_jacobi(const float* __restrict__ x,
                                                  float* __restrict__ Wg,
                                                  float* __restrict__ nrm2g,
                                                  float* __restrict__ sigg){
  __shared__ alignas(16) float col[64*JCOL];
  __shared__ float nr[64];
  const int lane = threadIdx.x;
  const int b = blockIdx.x;
  const float* mat = x + (size_t)b*NPOS;
  float a[64];
  float rsum = 0.f;
  #pragma unroll
  for (int i=0;i<64;++i){
    a[i] = 0.5f*(mat[(i<<6)+lane] + mat[(lane<<6)+i]);
    rsum += fabsf(a[i]);
  }
  // Gershgorin bound: sigma = max_i sum_j |A_ij| + 1  =>  A+sigma*I SPD
  #pragma unroll
  for (int off=1; off<64; off<<=1) rsum = fmaxf(rsum, __shfl_xor(rsum, off, 64));
  const float sigma = rsum + 1.0f;
  #pragma unroll
  for (int i=0;i<64;++i) a[i] += (i==lane) ? sigma : 0.0f;   // STATIC index

  float4* mc = (float4*)(col + lane*JCOL);
  #pragma unroll
  for (int q=0;q<16;++q){
    float4 v; v.x=a[4*q+0]; v.y=a[4*q+1]; v.z=a[4*q+2]; v.w=a[4*q+3];
    mc[q] = v;
  }
  float own = 0.f;
  #pragma unroll
  for (int i=0;i<64;++i) own = fmaf(a[i], a[i], own);
  nr[lane] = own;
  __syncthreads();

  #pragma unroll 1
  for (int sw=0; sw<NSWEEP; ++sw){
    own = 0.f;                                  // exact norm refresh per sweep
    #pragma unroll
    for (int i=0;i<64;++i) own = fmaf(a[i], a[i], own);
    nr[lane] = own;
    __syncthreads();
    int nrot = 0;
    #pragma unroll 1
    for (int m=1; m<64; ++m){
      const int p = lane ^ m;
      const float4* pc = (const float4*)(col + p*JCOL);
      float t[64];
      float d = 0.f;
      #pragma unroll
      for (int q=0;q<16;++q){
        float4 v = pc[q];
        t[4*q+0]=v.x; t[4*q+1]=v.y; t[4*q+2]=v.z; t[4*q+3]=v.w;
        d = fmaf(a[4*q+0], v.x, d);
        d = fmaf(a[4*q+1], v.y, d);
        d = fmaf(a[4*q+2], v.z, d);
        d = fmaf(a[4*q+3], v.w, d);
      }
      float oth = nr[p];
      // ---- force t[] + oth live in registers: after this point the compiler
      // may not assume LDS is unchanged, so re-reading col[] is unsound.
      asm volatile("" ::: "memory");
      bool rot = (d*d > JTH*own*oth);
      // angle (computed for all lanes; forced to identity when !rot)
      float tau = (oth - own)/(2.0f*d);
      float tt  = copysignf(1.0f, tau)/(fabsf(tau) + sqrtf(fmaf(tau,tau,1.0f)));
      float c   = 1.0f/sqrtf(fmaf(tt,tt,1.0f));
      float s   = tt*c;
      if (!rot){ c = 1.0f; s = 0.0f; tt = 0.0f; }   // identity; also kills 0/0 NaN
      own = fmaf(-tt, d, own);
      float ns = -s;
      #pragma unroll
      for (int i=0;i<64;++i) a[i] = fmaf(ns, t[i], c*a[i]);   // unconditional, zero LDS reads
      if (__any(rot)){
        ++nrot;
        if (rot){                       // only rotated columns rewrite their mirror
          #pragma unroll
          for (int q=0;q<16;++q){
            float4 v; v.x=a[4*q+0]; v.y=a[4*q+1]; v.z=a[4*q+2]; v.w=a[4*q+3];
            mc[q] = v;
          }
          nr[lane] = own;
        }
        __syncthreads();                // wave-uniform (block == one wave)
      }
    }
    if (nrot <= 2) break;   // near-converged: skip the pure-verification sweep
  }
  float nrm = 0.f;
  #pragma unroll
  for (int i=0;i<64;++i) nrm = fmaf(a[i],a[i],nrm);
  float* wp = Wg + (size_t)b*NPOS;
  #pragma unroll
  for (int i=0;i<64;++i) wp[(i<<6)+lane] = a[i];   // W row-major, coalesced
  nrm2g[(b<<6)+lane] = nrm;
  if (lane == 0) sigg[b] = sigma;
}

// ---------------------------------------------------------------- L = W diag(g/||w||^2) W^T (+ fused channel stats)
#define VP 68   // stride for b128 broadcast rows
#define WP 65   // stride for lane-varying b32 reads (2-way, free)
__global__ __launch_bounds__(256) void k_logm(float* __restrict__ WL,
                                              const float* __restrict__ nrm2g,
                                              const float* __restrict__ sigg,
                                              float* __restrict__ stats1){
  __shared__ alignas(16) float Vr[64*VP];
  __shared__ float Wr[64*WP];
  __shared__ float sc[64];
  __shared__ float red[4][2];
  const int b = blockIdx.x, tid = threadIdx.x;
  float* base = WL + (size_t)b*NPOS;
  if (tid < 64){
    float n2  = nrm2g[(b<<6)+tid];
    float lam = sqrtf(n2) - sigg[b];
    float g   = logf(fmaxf(lam, 1e-4f));
    sc[tid]   = g / n2;
  }
  __syncthreads();
  for (int idx=tid; idx<NPOS; idx+=256){
    int i = idx>>6, j = idx&63;
    float vv = base[idx];
    Vr[i*VP+j] = vv;
    Wr[i*WP+j] = sc[j]*vv;
  }
  __syncthreads();
  float s1 = 0.f, s2 = 0.f;
  for (int idx=tid; idx<NPOS; idx+=256){
    int i = idx>>6, k = idx&63;            // i wave-uniform, k = lane
    const float4* vrow = (const float4*)&Vr[i*VP];
    const float*  wrow = &Wr[k*WP];
    float4 acc = {0.f,0.f,0.f,0.f};
    #pragma unroll
    for (int j=0;j<16;++j){
      float4 a4 = vrow[j];                 // broadcast (same addr all lanes)
      acc.x = fmaf(a4.x, wrow[4*j+0], acc.x);
      acc.y = fmaf(a4.y, wrow[4*j+1], acc.y);
      acc.z = fmaf(a4.z, wrow[4*j+2], acc.z);
      acc.w = fmaf(a4.w, wrow[4*j+3], acc.w);
    }
    float L = (acc.x+acc.y)+(acc.z+acc.w);
    base[idx] = L;                          // overwrite W with L
    s1 += L; s2 = fmaf(L, L, s2);
  }
  for (int off=32; off; off>>=1){ s1 += __shfl_down(s1,off,64); s2 += __shfl_down(s2,off,64); }
  const int w = tid>>6, lane = tid&63;
  if (lane == 0){ red[w][0] = s1; red[w][1] = s2; }
  __syncthreads();
  if (tid == 0){
    s1 = red[0][0]+red[1][0]+red[2][0]+red[3][0];
    s2 = red[0][1]+red[1][1]+red[2][1]+red[3][1];
    float mean = s1*(1.0f/4096.0f);
    float var  = s2*(1.0f/4096.0f) - mean*mean;
    float sd   = sqrtf(fmaxf(var, 0.f));
    int n = b/CC, ch = b - n*CC;
    stats1[(n*32+ch)*2+0] = mean;
    stats1[(n*32+ch)*2+1] = 1.0f/fmaxf(sd, 1e-3f);
  }
}

// ---------------------------------------------------------------- pass 1: h2 stats
// Dynamic-j operands live in a per-thread LDS slot so the j-loops stay ROLLED
// while register accumulators t[k]/eu[k] stay STATIC (kills the r5 spill).
__global__ __launch_bounds__(256) void k_pass1(const float* __restrict__ logT,
    const float* __restrict__ em3, const float* __restrict__ stats1,
    const float* __restrict__ w2, const float* __restrict__ b2,
    const float* __restrict__ w3, const float* __restrict__ b3,
    float* __restrict__ s2raw){
  const int n = blockIdx.x;
  const int tid = threadIdx.x;
  const int pp = (blockIdx.y<<8) + tid;
  __shared__ alignas(16) float w2s[1024];
  __shared__ alignas(16) float w3s[1024];
  __shared__ float b2s[32], b3s[32], ms[32], rs[32], e3[10];
  __shared__ float eus[256*EUP];
  __shared__ float redp[4][64];
  for (int i=tid;i<1024;i+=256){ w2s[i]=w2[i]; w3s[i]=w3[i]; }
  if (tid<32){ b2s[tid]=b2[tid]; b3s[tid]=b3[tid];
    ms[tid]=stats1[(n*32+tid)*2]; rs[tid]=stats1[(n*32+tid)*2+1]; }
  if (tid<10) e3[tid]=em3[tid];
  __syncthreads();
  float eu[32], t[32];
  float* myeu = eus + tid*EUP;
  const float* base = logT + (size_t)n*CC*NPOS + pp;
  #pragma unroll
  for (int c=0;c<22;++c) eu[c] = base[c*NPOS];
  #pragma unroll
  for (int c=0;c<10;++c) eu[22+c] = e3[c];
  #pragma unroll
  for (int j=0;j<32;++j) myeu[j] = (eu[j]-ms[j])*rs[j];
  #pragma unroll
  for (int k=0;k<32;++k) t[k] = b2s[k];
  #pragma unroll 1
  for (int j=0;j<32;++j){
    float nj = myeu[j];
    const float4* wr = (const float4*)(w2s + (j<<5));
    #pragma unroll
    for (int q=0;q<8;++q){
      float4 w4 = wr[q];
      t[4*q+0] = fmaf(nj, w4.x, t[4*q+0]);
      t[4*q+1] = fmaf(nj, w4.y, t[4*q+1]);
      t[4*q+2] = fmaf(nj, w4.z, t[4*q+2]);
      t[4*q+3] = fmaf(nj, w4.w, t[4*q+3]);
    }
  }
  #pragma unroll
  for (int k=0;k<32;++k) myeu[k] = fmaxf(t[k], 0.f);
  #pragma unroll
  for (int k=0;k<32;++k) eu[k] += b3s[k];
  #pragma unroll 1
  for (int j=0;j<32;++j){
    float tj = myeu[j];
    const float4* wr = (const float4*)(w3s + (j<<5));
    #pragma unroll
    for (int q=0;q<8;++q){
      float4 w4 = wr[q];
      eu[4*q+0] = fmaf(tj, w4.x, eu[4*q+0]);
      eu[4*q+1] = fmaf(tj, w4.y, eu[4*q+1]);
      eu[4*q+2] = fmaf(tj, w4.z, eu[4*q+2]);
      eu[4*q+3] = fmaf(tj, w4.w, eu[4*q+3]);
    }
  }
  const int w = tid>>6, lane = tid&63;
  #pragma unroll
  for (int k=0;k<32;++k){
    float v = eu[k], v2 = eu[k]*eu[k];
    for (int off=32; off; off>>=1){ v += __shfl_down(v,off,64); v2 += __shfl_down(v2,off,64); }
    if (lane == 0){ redp[w][2*k] = v; redp[w][2*k+1] = v2; }
  }
  __syncthreads();
  if (tid < 64){
    float v = redp[0][tid]+redp[1][tid]+redp[2][tid]+redp[3][tid];
    atomicAdd(&s2raw[(n<<6)+tid], v);
  }
}

// ---------------------------------------------------------------- finalize h2 stats
__global__ void k_fin2(const float* __restrict__ s2raw, float* __restrict__ stats2){
  int i = blockIdx.x*256 + threadIdx.x;
  if (i < NS*32){
    float s = s2raw[2*i], sq = s2raw[2*i+1];
    float mean = s*(1.0f/4096.0f);
    float var  = sq*(1.0f/4096.0f) - mean*mean;
    float sd   = sqrtf(fmaxf(var, 0.f));
    stats2[2*i]   = mean;
    stats2[2*i+1] = 1.0f/fmaxf(sd, 1e-3f);
  }
}

// ---------------------------------------------------------------- pass 2: h3 accumulation (same rolled-j structure)
__global__ __launch_bounds__(256) void k_pass2(const float* __restrict__ logT,
    const float* __restrict__ em3, const float* __restrict__ stats1, const float* __restrict__ stats2,
    const float* __restrict__ w2, const float* __restrict__ b2,
    const float* __restrict__ w3, const float* __restrict__ b3,
    const float* __restrict__ w4, const float* __restrict__ b4,
    const float* __restrict__ w5, const float* __restrict__ b5,
    float* __restrict__ cov3){
  const int n = blockIdx.x;
  const int tid = threadIdx.x;
  const int pp = (blockIdx.y<<8) + tid;
  __shared__ alignas(16) float w2s[1024];
  __shared__ alignas(16) float w3s[1024];
  __shared__ alignas(16) float w4s[1024];
  __shared__ alignas(16) float w5s[1024];
  __shared__ float b2s[32], b3s[32], b4s[32], b5s[32];
  __shared__ float m1[32], r1[32], m2[32], r2[32], e3[10];
  __shared__ float eus[256*EUP];
  __shared__ float redp[4][32];
  for (int i=tid;i<1024;i+=256){ w2s[i]=w2[i]; w3s[i]=w3[i]; w4s[i]=w4[i]; w5s[i]=w5[i]; }
  if (tid<32){ b2s[tid]=b2[tid]; b3s[tid]=b3[tid]; b4s[tid]=b4[tid]; b5s[tid]=b5[tid];
    m1[tid]=stats1[(n*32+tid)*2]; r1[tid]=stats1[(n*32+tid)*2+1];
    m2[tid]=stats2[(n*32+tid)*2]; r2[tid]=stats2[(n*32+tid)*2+1]; }
  if (tid<10) e3[tid]=em3[tid];
  __syncthreads();
  float eu[32], t[32];
  float* myeu = eus + tid*EUP;
  const float* base = logT + (size_t)n*CC*NPOS + pp;
  #pragma unroll
  for (int c=0;c<22;++c) eu[c] = base[c*NPOS];
  #pragma unroll
  for (int c=0;c<10;++c) eu[22+c] = e3[c];
  // --- block 1 ---
  #pragma unroll
  for (int j=0;j<32;++j) myeu[j] = (eu[j]-m1[j])*r1[j];
  #pragma unroll
  for (int k=0;k<32;++k) t[k] = b2s[k];
  #pragma unroll 1
  for (int j=0;j<32;++j){
    float nj = myeu[j];
    const float4* wr = (const float4*)(w2s + (j<<5));
    #pragma unroll
    for (int q=0;q<8;++q){
      float4 w4v = wr[q];
      t[4*q+0] = fmaf(nj, w4v.x, t[4*q+0]);
      t[4*q+1] = fmaf(nj, w4v.y, t[4*q+1]);
      t[4*q+2] = fmaf(nj, w4v.z, t[4*q+2]);
      t[4*q+3] = fmaf(nj, w4v.w, t[4*q+3]);
    }
  }
  #pragma unroll
  for (int k=0;k<32;++k) myeu[k] = fmaxf(t[k], 0.f);
  #pragma unroll
  for (int k=0;k<32;++k) eu[k] += b3s[k];
  #pragma unroll 1
  for (int j=0;j<32;++j){
    float tj = myeu[j];
    const float4* wr = (const float4*)(w3s + (j<<5));
    #pragma unroll
    for (int q=0;q<8;++q){
      float4 w4v = wr[q];
      eu[4*q+0] = fmaf(tj, w4v.x, eu[4*q+0]);
      eu[4*q+1] = fmaf(tj, w4v.y, eu[4*q+1]);
      eu[4*q+2] = fmaf(tj, w4v.z, eu[4*q+2]);
      eu[4*q+3] = fmaf(tj, w4v.w, eu[4*q+3]);
    }
  }
  // --- block 2 ---
  #pragma unroll
  for (int j=0;j<32;++j) myeu[j] = (eu[j]-m2[j])*r2[j];
  #pragma unroll
  for (int k=0;k<32;++k) t[k] = b4s[k];
  #pragma unroll 1
  for (int j=0;j<32;++j){
    float nj = myeu[j];
    const float4* wr = (const float4*)(w4s + (j<<5));
    #pragma unroll
    for (int q=0;q<8;++q){
      float4 w4v = wr[q];
      t[4*q+0] = fmaf(nj, w4v.x, t[4*q+0]);
      t[4*q+1] = fmaf(nj, w4v.y, t[4*q+1]);
      t[4*q+2] = fmaf(nj, w4v.z, t[4*q+2]);
      t[4*q+3] = fmaf(nj, w4v.w, t[4*q+3]);
    }
  }
  #pragma unroll
  for (int k=0;k<32;++k) myeu[k] = fmaxf(t[k], 0.f);
  #pragma unroll
  for (int k=0;k<32;++k) eu[k] += b5s[k];
  #pragma unroll 1
  for (int j=0;j<32;++j){
    float tj = myeu[j];
    const float4* wr = (const float4*)(w5s + (j<<5));
    #pragma unroll
    for (int q=0;q<8;++q){
      float4 w4v = wr[q];
      eu[4*q+0] = fmaf(tj, w4v.x, eu[4*q+0]);
      eu[4*q+1] = fmaf(tj, w4v.y, eu[4*q+1]);
      eu[4*q+2] = fmaf(tj, w4v.z, eu[4*q+2]);
      eu[4*q+3] = fmaf(tj, w4v.w, eu[4*q+3]);
    }
  }
  const int w = tid>>6, lane = tid&63;
  #pragma unroll
  for (int k=0;k<32;++k){
    float v = eu[k];
    for (int off=32; off; off>>=1) v += __shfl_down(v,off,64);
    if (lane == 0) redp[w][k] = v;
  }
  __syncthreads();
  if (tid < 32){
    float v = redp[0][tid]+redp[1][tid]+redp[2][tid]+redp[3][tid];
    atomicAdd(&cov3[(n<<5)+tid], v);
  }
}

// ---------------------------------------------------------------- head: mean -> matmul -> softmax
__global__ void k_out(const float* __restrict__ cov3, const float* __restrict__ w,
                      float* __restrict__ out){
  __shared__ float wsm[224];
  const int tid = threadIdx.x;
  if (tid < 224) wsm[tid] = w[tid];
  __syncthreads();
  const int n = tid;
  float l[7];
  #pragma unroll
  for (int c=0;c<7;++c) l[c] = 0.f;
  #pragma unroll
  for (int ch=0;ch<32;++ch){
    float v = cov3[(n<<5)+ch]*(1.0f/4096.0f);
    #pragma unroll
    for (int c=0;c<7;++c) l[c] = fmaf(v, wsm[ch*7+c], l[c]);
  }
  float mx = l[0];
  #pragma unroll
  for (int c=1;c<7;++c) mx = fmaxf(mx, l[c]);
  float ssum = 0.f;
  #pragma unroll
  for (int c=0;c<7;++c){ l[c] = expf(l[c]-mx); ssum += l[c]; }
  float inv = 1.0f/ssum;
  #pragma unroll
  for (int c=0;c<7;++c) out[n*7+c] = l[c]*inv;
}

// ----------------------------------------------------------------
extern "C" void kernel_launch(void* const* d_in, const int* in_sizes, int n_in,
                              void* d_out, int out_size, void* d_ws, size_t ws_size,
                              hipStream_t stream){
  const float* x   = (const float*)d_in[0];
  const int*   Mp  = (const int*)  d_in[1];
  const float* w   = (const float*)d_in[2];
  const float* w2  = (const float*)d_in[3];
  const float* b2  = (const float*)d_in[4];
  const float* w3  = (const float*)d_in[5];
  const float* b3  = (const float*)d_in[6];
  const float* w4  = (const float*)d_in[7];
  const float* b4  = (const float*)d_in[8];
  const float* w5  = (const float*)d_in[9];
  const float* b5  = (const float*)d_in[10];
  const float* we1 = (const float*)d_in[11];
  const float* be1 = (const float*)d_in[12];
  const float* we2 = (const float*)d_in[13];
  const float* be2 = (const float*)d_in[14];
  const float* we3 = (const float*)d_in[15];
  const float* be3 = (const float*)d_in[16];
  const float* lng = (const float*)d_in[17];
  const float* lnb = (const float*)d_in[18];

  float* wsf    = (float*)d_ws;
  float* WL     = wsf;                           // [NMAT,4096] W then L in place (92.3 MB)
  float* nrm2g  = WL + (size_t)NMAT*NPOS;        // [NMAT,64]
  float* sigg   = nrm2g + (size_t)NMAT*64;       // [NMAT]
  float* em3    = sigg + NMAT;                   // 16
  float* stats1 = em3 + 16;                      // [N,32,2]
  float* s2raw  = stats1 + NS*64;                // [N,32,2] accum (zeroed)
  float* cov3   = s2raw + NS*64;                 // [N,32]   accum (zeroed)
  float* stats2 = cov3 + NS*32;                  // [N,32,2]

  hipMemsetAsync(s2raw, 0, (size_t)(NS*64 + NS*32)*sizeof(float), stream);

  k_embed <<<1, 256, 0, stream>>>(we1,be1,we2,be2,we3,be3,lng,lnb,Mp,em3,stats1);
  k_jacobi<<<NMAT, 64, 0, stream>>>(x, WL, nrm2g, sigg);
  k_logm  <<<NMAT, 256, 0, stream>>>(WL, nrm2g, sigg, stats1);
  k_pass1 <<<dim3(NS,16), 256, 0, stream>>>(WL, em3, stats1, w2,b2,w3,b3, s2raw);
  k_fin2  <<<(NS*32+255)/256, 256, 0, stream>>>(s2raw, stats2);
  k_pass2 <<<dim3(NS,16), 256, 0, stream>>>(WL, em3, stats1, stats2,
                                            w2,b2,w3,b3,w4,b4,w5,b5, cov3);
  k_out   <<<1, 256, 0, stream>>>(cov3, w, (float*)d_out);
}